// Round 15
// baseline (264.649 us; speedup 1.0000x reference)
//
#include <hip/hip_runtime.h>
#include <hip/hip_bf16.h>

#define B_ 4
#define N_ 2048
#define H_ 8
#define C_ 768
#define CV_ 512
#define DH_ 96
#define DV_ 64
// SCALE = 32^-0.5 = 2^-2.5 ; K2E = SCALE * log2(e) = 0.25503486...
#define K2E_ 0.2550348620270320f

using bf16x8 = __attribute__((ext_vector_type(8))) short;
using f16x8  = __attribute__((ext_vector_type(8))) _Float16;
using f32x4  = __attribute__((ext_vector_type(4))) float;
using u16x4  = __attribute__((ext_vector_type(4))) unsigned short;

__device__ __forceinline__ unsigned short f2bf(float f) {
  union { float f; unsigned u; } x; x.f = f;
  unsigned r = x.u + 0x7fffu + ((x.u >> 16) & 1u);
  return (unsigned short)(r >> 16);
}
__device__ __forceinline__ float bf2f(unsigned short b) {
  union { unsigned u; float f; } x; x.u = ((unsigned)b) << 16;
  return x.f;
}
__device__ __forceinline__ void gload16(const void* g, void* l) {
  __builtin_amdgcn_global_load_lds(
      (const __attribute__((address_space(1))) void*)g,
      (__attribute__((address_space(3))) void*)l, 16, 0, 0);
}

#define MFMA_BF(a,b,c) __builtin_amdgcn_mfma_f32_16x16x32_bf16((a),(b),(c),0,0,0)
#define MFMA_F16(a,b,c) __builtin_amdgcn_mfma_f32_16x16x32_f16((a),(b),(c),0,0,0)

// ---------------------------------------------------------------------------
// f32 -> fp16 conversion, two tensors (blockIdx.y selects). 8 elems/thread.
// ---------------------------------------------------------------------------
__global__ __launch_bounds__(256) void convert2_f16_kernel(
    const float* __restrict__ in0, const float* __restrict__ in1,
    _Float16* __restrict__ o0, _Float16* __restrict__ o1)
{
  const float* in = blockIdx.y ? in1 : in0;
  _Float16* out = blockIdx.y ? o1 : o0;
  const size_t i8 = ((size_t)blockIdx.x * 256 + threadIdx.x) * 8;
  float4 v0 = *(const float4*)(in + i8);
  float4 v1 = *(const float4*)(in + i8 + 4);
  f16x8 o;
  o[0] = (_Float16)v0.x; o[1] = (_Float16)v0.y;
  o[2] = (_Float16)v0.z; o[3] = (_Float16)v0.w;
  o[4] = (_Float16)v1.x; o[5] = (_Float16)v1.y;
  o[6] = (_Float16)v1.z; o[7] = (_Float16)v1.w;
  *(f16x8*)(out + i8) = o;
}

// ---------------------------------------------------------------------------
// f32 -> bf16 conversion. 8 elems/thread.
// ---------------------------------------------------------------------------
__global__ __launch_bounds__(256) void convert_bf16_kernel(
    const float* __restrict__ in, unsigned short* __restrict__ out)
{
  const size_t i8 = ((size_t)blockIdx.x * 256 + threadIdx.x) * 8;
  float4 v0 = *(const float4*)(in + i8);
  float4 v1 = *(const float4*)(in + i8 + 4);
  u16x4 a, b;
  a[0] = f2bf(v0.x); a[1] = f2bf(v0.y); a[2] = f2bf(v0.z); a[3] = f2bf(v0.w);
  b[0] = f2bf(v1.x); b[1] = f2bf(v1.y); b[2] = f2bf(v1.z); b[3] = f2bf(v1.w);
  *(u16x4*)(out + i8) = a;
  *(u16x4*)(out + i8 + 4) = b;
}

// ---------------------------------------------------------------------------
// fp16 GEMM for Q and K projections in one dispatch (blockIdx.z selects).
// O = scale * (X @ W^T). 128x128 tile, BK=64, global_load_lds, linear LDS.
// Output fp16 at [(b*8+h)*2048+n]*96+d.  Q gets scale=K2E.
// ---------------------------------------------------------------------------
__global__ __launch_bounds__(256) void proj_qk2_kernel(
    const _Float16* __restrict__ Xq, const _Float16* __restrict__ Xk,
    const _Float16* __restrict__ Wqf, const _Float16* __restrict__ Wkf,
    _Float16* __restrict__ Oq, _Float16* __restrict__ Ok)
{
  __shared__ __align__(16) _Float16 Ah[128 * 64];
  __shared__ __align__(16) _Float16 Bh[128 * 64];

  const int zq = blockIdx.z;
  const _Float16* X = zq ? Xk : Xq;
  const _Float16* W = zq ? Wkf : Wqf;
  _Float16* O = zq ? Ok : Oq;
  const float scale = zq ? 1.0f : K2E_;

  const int mb = blockIdx.x * 128, nb = blockIdx.y * 128;
  const int t = threadIdx.x, w = t >> 6, lane = t & 63;
  const int fr = lane & 15, g = lane >> 4;
  const int wr = w >> 1, wc = w & 1;

  int offA[4], offB[4];
  unsigned ldsB[4];
#pragma unroll
  for (int j = 0; j < 4; ++j) {
    int lin = ((w * 4 + j) << 10) + (lane << 4);
    int r = lin >> 7, ce = (lin & 127) >> 1;
    offA[j] = (mb + r) * C_ + ce;
    offB[j] = (nb + r) * C_ + ce;
    ldsB[j] = (unsigned)((w * 4 + j) << 10);
  }

  f32x4 acc[4][4];
#pragma unroll
  for (int m = 0; m < 4; ++m)
#pragma unroll
    for (int n = 0; n < 4; ++n) acc[m][n] = (f32x4){0.f, 0.f, 0.f, 0.f};

  for (int kt = 0; kt < C_ / 64; ++kt) {
    const int kb = kt * 64;
    __syncthreads();
#pragma unroll
    for (int j = 0; j < 4; ++j) {
      gload16(X + offA[j] + kb, (char*)Ah + ldsB[j]);
      gload16(W + offB[j] + kb, (char*)Bh + ldsB[j]);
    }
    __syncthreads();
#pragma unroll
    for (int s = 0; s < 2; ++s) {
      const int cbyte = s * 64 + g * 16;
      f16x8 ah[4], bh2[4];
#pragma unroll
      for (int m = 0; m < 4; ++m)
        ah[m] = *(const f16x8*)((const char*)Ah + (wr * 64 + m * 16 + fr) * 128 + cbyte);
#pragma unroll
      for (int n = 0; n < 4; ++n)
        bh2[n] = *(const f16x8*)((const char*)Bh + (wc * 64 + n * 16 + fr) * 128 + cbyte);
#pragma unroll
      for (int m = 0; m < 4; ++m)
#pragma unroll
        for (int n = 0; n < 4; ++n)
          acc[m][n] = MFMA_F16(ah[m], bh2[n], acc[m][n]);
    }
  }

#pragma unroll
  for (int m = 0; m < 4; ++m) {
    const int Mrow = mb + wr * 64 + m * 16 + g * 4;
#pragma unroll
    for (int n = 0; n < 4; ++n) {
      const int co = nb + wc * 64 + n * 16 + fr;
      const int h = co / DH_, d = co - h * DH_;
#pragma unroll
      for (int r = 0; r < 4; ++r) {
        const int M = Mrow + r;
        const int b = M >> 11, nn = M & (N_ - 1);
        O[((size_t)((b * H_ + h) * N_ + nn)) * DH_ + d] = (_Float16)(acc[m][n][r] * scale);
      }
    }
  }
}

// ---------------------------------------------------------------------------
// V projection, 128x128 tile bf16 (m97 structure), storing V^T:
// OvT[(b*8+h)*64 + d][n].  X:(8192,512) bf16, W:(512,512) bf16.
// ---------------------------------------------------------------------------
__global__ __launch_bounds__(256) void proj_v128_kernel(
    const unsigned short* __restrict__ X, const unsigned short* __restrict__ W,
    unsigned short* __restrict__ OvT)
{
  __shared__ __align__(16) unsigned short Ah[128 * 64];
  __shared__ __align__(16) unsigned short Bh[128 * 64];

  const int mb = blockIdx.x * 128, nb = blockIdx.y * 128;
  const int t = threadIdx.x, w = t >> 6, lane = t & 63;
  const int fr = lane & 15, g = lane >> 4;
  const int wr = w >> 1, wc = w & 1;

  int offA[4], offB[4];
  unsigned ldsB[4];
#pragma unroll
  for (int j = 0; j < 4; ++j) {
    int lin = ((w * 4 + j) << 10) + (lane << 4);
    int r = lin >> 7, ce = (lin & 127) >> 1;
    offA[j] = (mb + r) * CV_ + ce;
    offB[j] = (nb + r) * CV_ + ce;
    ldsB[j] = (unsigned)((w * 4 + j) << 10);
  }

  f32x4 acc[4][4];
#pragma unroll
  for (int m = 0; m < 4; ++m)
#pragma unroll
    for (int n = 0; n < 4; ++n) acc[m][n] = (f32x4){0.f, 0.f, 0.f, 0.f};

  for (int kt = 0; kt < CV_ / 64; ++kt) {
    const int kb = kt * 64;
    __syncthreads();
#pragma unroll
    for (int j = 0; j < 4; ++j) {
      gload16(X + offA[j] + kb, (char*)Ah + ldsB[j]);
      gload16(W + offB[j] + kb, (char*)Bh + ldsB[j]);
    }
    __syncthreads();
#pragma unroll
    for (int s = 0; s < 2; ++s) {
      const int cbyte = s * 64 + g * 16;
      bf16x8 ah[4], bh2[4];
#pragma unroll
      for (int m = 0; m < 4; ++m)
        ah[m] = *(const bf16x8*)((const char*)Ah + (wr * 64 + m * 16 + fr) * 128 + cbyte);
#pragma unroll
      for (int n = 0; n < 4; ++n)
        bh2[n] = *(const bf16x8*)((const char*)Bh + (wc * 64 + n * 16 + fr) * 128 + cbyte);
#pragma unroll
      for (int m = 0; m < 4; ++m)
#pragma unroll
        for (int n = 0; n < 4; ++n)
          acc[m][n] = MFMA_BF(ah[m], bh2[n], acc[m][n]);
    }
  }

  // V^T store: 4 consecutive n per lane -> one b64 store
#pragma unroll
  for (int m = 0; m < 4; ++m) {
    const int M0 = mb + wr * 64 + m * 16 + g * 4;
    const int b = M0 >> 11, nn = M0 & (N_ - 1);
#pragma unroll
    for (int n = 0; n < 4; ++n) {
      const int co = nb + wc * 64 + n * 16 + fr;
      const int h = co >> 6, d = co & 63;
      u16x4 pk;
#pragma unroll
      for (int r = 0; r < 4; ++r) pk[r] = f2bf(acc[m][n][r]);
      *(u16x4*)(OvT + ((size_t)((b * H_ + h) * DV_ + d)) * N_ + nn) = pk;
    }
  }
}

// ---------------------------------------------------------------------------
// Mask pre-pass: bf16 copy + per-row sum. One block per (b,n) row.
// ---------------------------------------------------------------------------
__global__ __launch_bounds__(256) void mask_prep_kernel(
    const float* __restrict__ masks, unsigned short* __restrict__ mask_bf,
    float* __restrict__ msum)
{
  const int row = blockIdx.x;
  const int t = threadIdx.x;
  const float* p = masks + (size_t)row * N_;
  unsigned short* o = mask_bf + (size_t)row * N_;
  float4 v0 = *(const float4*)(p + t * 8);
  float4 v1 = *(const float4*)(p + t * 8 + 4);
  float s = v0.x + v0.y + v0.z + v0.w + v1.x + v1.y + v1.z + v1.w;
  u16x4 a, b;
  a[0] = f2bf(v0.x); a[1] = f2bf(v0.y); a[2] = f2bf(v0.z); a[3] = f2bf(v0.w);
  b[0] = f2bf(v1.x); b[1] = f2bf(v1.y); b[2] = f2bf(v1.z); b[3] = f2bf(v1.w);
  *(u16x4*)(o + t * 8) = a;
  *(u16x4*)(o + t * 8 + 4) = b;
#pragma unroll
  for (int ofs = 32; ofs > 0; ofs >>= 1) s += __shfl_down(s, ofs, 64);
  __shared__ float ws4[4];
  if ((t & 63) == 0) ws4[t >> 6] = s;
  __syncthreads();
  if (t == 0) msum[row] = ws4[0] + ws4[1] + ws4[2] + ws4[3];
}

// ---------------------------------------------------------------------------
// Attention: block = (qtile, h, b), 128 threads = 2 waves x 64 q-rows.
// Fat waves minimize duplicated LDS reads: kh read once per (a,s) feeds 4
// q-frag MFMAs; Vs read once per (s2,dt) feeds 4 q-frags. QBLK=128, LDS
// 38.9KB -> 4 blocks/CU. Q/K fp16, P/mask/V bf16. Q pre-scaled by K2E.
// ---------------------------------------------------------------------------
__global__ __launch_bounds__(128) void attn_kernel(
    const _Float16* __restrict__ Qf, const _Float16* __restrict__ Kf,
    const unsigned short* __restrict__ VT,  const unsigned short* __restrict__ mask_bf,
    const float* __restrict__ msum, float* __restrict__ out)
{
  __shared__ __align__(16) _Float16 Ks[64][100];
  __shared__ __align__(16) unsigned short Vs[64][68];    // V^T tile: [d][k]
  __shared__ __align__(16) unsigned short Ps[128][68];   // P: [q][k_local]

  const int qbase = blockIdx.x * 128;
  const int h = blockIdx.y, b = blockIdx.z;
  const int t = threadIdx.x;
  const int w = t >> 6, lane = t & 63;
  const int fr = lane & 15, g = lane >> 4;
  const int kof = g * 8;

  const size_t bh = (size_t)(b * H_ + h);
  const _Float16* Kf_p = Kf + bh * N_ * DH_;
  const unsigned short* VT_p = VT + bh * DV_ * N_;

  // Q fragments: 4 q-frags (16 rows each) x 3 k-steps
  f16x8 qh[4][3];
  unsigned mrow_off[4];
#pragma unroll
  for (int qf = 0; qf < 4; ++qf) {
    const int qrow = qbase + w * 64 + qf * 16 + fr;
    mrow_off[qf] = (unsigned)(qrow * N_);
#pragma unroll
    for (int s = 0; s < 3; ++s)
      qh[qf][s] = *(const f16x8*)(Qf + (bh * N_ + qrow) * DH_ + s * 32 + kof);
  }
  const unsigned short* mask_b = mask_bf + (size_t)b * N_ * N_;

  // staging: K 64x96 f16 = 768 16B chunks over 128 threads (6 ea);
  //          V 64x64 bf16 = 512 chunks (4 ea)
  int kr[6], kc[6], vr[4], vc[4];
#pragma unroll
  for (int i = 0; i < 6; ++i) { int c = t + 128 * i; kr[i] = c / 12; kc[i] = (c % 12) * 8; }
#pragma unroll
  for (int i = 0; i < 4; ++i) { int c = t + 128 * i; vr[i] = c >> 3; vc[i] = (c & 7) * 8; }

  f16x8 pk[6];
  bf16x8 pv[4];
  auto load_regs = [&](int kb) {
#pragma unroll
    for (int i = 0; i < 6; ++i)
      pk[i] = *(const f16x8*)(Kf_p + (size_t)(kb + kr[i]) * DH_ + kc[i]);
#pragma unroll
    for (int i = 0; i < 4; ++i)
      pv[i] = *(const bf16x8*)(VT_p + (size_t)vr[i] * N_ + kb + vc[i]);
  };

  f32x4 oacc[4][4];
#pragma unroll
  for (int qf = 0; qf < 4; ++qf)
#pragma unroll
    for (int i = 0; i < 4; ++i) oacc[qf][i] = (f32x4){0.f, 0.f, 0.f, 0.f};
  float z[4] = {0.f, 0.f, 0.f, 0.f};

  load_regs(0);

  for (int kt = 0; kt < N_ / 64; ++kt) {
    const int kb = kt * 64;
    __syncthreads();
#pragma unroll
    for (int i = 0; i < 6; ++i) *(f16x8*)&Ks[kr[i]][kc[i]] = pk[i];
#pragma unroll
    for (int i = 0; i < 4; ++i) *(bf16x8*)&Vs[vr[i]][vc[i]] = pv[i];
    __syncthreads();

    if (kt + 1 < N_ / 64) load_regs(kb + 64);

    // QK^T + softmax, one 16-k group (a) at a time: kh read once per (a,s),
    // feeds 4 q-frag MFMAs -> 4x less K-read traffic than 16q/wave.
#pragma unroll
    for (int a = 0; a < 4; ++a) {
      f16x8 kh[3];
#pragma unroll
      for (int s = 0; s < 3; ++s)
        kh[s] = *(const f16x8*)&Ks[a * 16 + fr][s * 32 + kof];
      f32x4 sacc[4];
#pragma unroll
      for (int qf = 0; qf < 4; ++qf) sacc[qf] = (f32x4){0.f, 0.f, 0.f, 0.f};
#pragma unroll
      for (int s = 0; s < 3; ++s)
#pragma unroll
        for (int qf = 0; qf < 4; ++qf)
          sacc[qf] = MFMA_F16(kh[s], qh[qf][s], sacc[qf]);

      // P = exp2(S) (Q pre-scaled); Z += P; Ps = bf16(P*mask), packed cvt
#pragma unroll
      for (int qf = 0; qf < 4; ++qf) {
        u16x4 mk = *(const u16x4*)(mask_b + mrow_off[qf] + kb + a * 16 + g * 4);
        float e0 = exp2f(sacc[qf][0]);
        float e1 = exp2f(sacc[qf][1]);
        float e2 = exp2f(sacc[qf][2]);
        float e3 = exp2f(sacc[qf][3]);
        z[qf] += (e0 + e1) + (e2 + e3);
        union { __hip_bfloat162 h; unsigned u; } c01, c23;
        c01.h = __float22bfloat162_rn(make_float2(e0 * bf2f(mk[0]), e1 * bf2f(mk[1])));
        c23.h = __float22bfloat162_rn(make_float2(e2 * bf2f(mk[2]), e3 * bf2f(mk[3])));
        *(uint2*)&Ps[w * 64 + qf * 16 + fr][a * 16 + g * 4] = make_uint2(c01.u, c23.u);
      }
    }

    // O += P V  (Ps rows wave-private; vb read once feeds 4 q-frags)
#pragma unroll
    for (int s2 = 0; s2 < 2; ++s2) {
      bf16x8 pa[4];
#pragma unroll
      for (int qf = 0; qf < 4; ++qf)
        pa[qf] = *(const bf16x8*)&Ps[w * 64 + qf * 16 + fr][s2 * 32 + kof];
#pragma unroll
      for (int dt = 0; dt < 4; ++dt) {
        bf16x8 vb = *(const bf16x8*)&Vs[dt * 16 + fr][s2 * 32 + kof];
#pragma unroll
        for (int qf = 0; qf < 4; ++qf)
          oacc[qf][dt] = MFMA_BF(pa[qf], vb, oacc[qf][dt]);
      }
    }
  }

  // Z: reduce across the 4 k-row groups (lanes fr, fr+16, fr+32, fr+48)
#pragma unroll
  for (int qf = 0; qf < 4; ++qf) {
    z[qf] += __shfl_xor(z[qf], 16, 64);
    z[qf] += __shfl_xor(z[qf], 32, 64);
  }

  // epilogue: output rows are q16 = g*4+r; Z lives at lane fr=q16
#pragma unroll
  for (int qf = 0; qf < 4; ++qf) {
#pragma unroll
    for (int r = 0; r < 4; ++r) {
      int q = qbase + w * 64 + qf * 16 + g * 4 + r;
      float Z = __shfl(z[qf], g * 4 + r, 64);
      float inv = 1.0f / (Z * 8.0f * msum[b * N_ + q]);
#pragma unroll
      for (int dt = 0; dt < 4; ++dt)
        out[((size_t)b * N_ + q) * CV_ + h * DV_ + dt * 16 + fr] = oacc[qf][dt][r] * inv;
    }
  }
}

// ---------------------------------------------------------------------------
extern "C" void kernel_launch(void* const* d_in, const int* in_sizes, int n_in,
                              void* d_out, int out_size, void* d_ws, size_t ws_size,
                              hipStream_t stream)
{
  (void)in_sizes; (void)n_in; (void)out_size; (void)ws_size;
  const float* q     = (const float*)d_in[0];
  const float* k     = (const float*)d_in[1];
  const float* v     = (const float*)d_in[2];
  const float* masks = (const float*)d_in[3];
  const float* Wq    = (const float*)d_in[4];
  const float* Wk    = (const float*)d_in[5];
  const float* Wv    = (const float*)d_in[6];
  float* out = (float*)d_out;

  char* ws = (char*)d_ws;
  const size_t qk_elems = (size_t)B_ * N_ * C_;        // 6,291,456
  const size_t w_elems  = (size_t)C_ * C_;             // 589,824
  const size_t v_elems  = (size_t)B_ * N_ * CV_;       // 4,194,304
  const size_t wv_elems = (size_t)CV_ * CV_;           // 262,144
  const size_t qk_bytes = qk_elems * 2;                // 12,582,912
  const size_t w_bytes  = w_elems * 2;                 // 1,179,648
  const size_t vb_bytes = v_elems * 2;                 // 8,388,608
  const size_t wv_bytes = wv_elems * 2;                // 524,288
  const size_t m_bytes  = (size_t)B_ * N_ * N_ * 2;    // 33,554,432

  // region0: proj-phase temporaries, later overwritten by mbf (mask_prep).
  unsigned short* mbf = (unsigned short*)ws;
  _Float16* Xq  = (_Float16*)ws;
  _Float16* Xk  = (_Float16*)(ws + qk_bytes);
  _Float16* Wqf = (_Float16*)(ws + 2 * qk_bytes);
  _Float16* Wkf = (_Float16*)(ws + 2 * qk_bytes + w_bytes);
  unsigned short* vb  = (unsigned short*)(ws + 2 * qk_bytes + 2 * w_bytes);
  unsigned short* Wvb = (unsigned short*)(ws + 2 * qk_bytes + 2 * w_bytes + vb_bytes);
  size_t r0 = 2 * qk_bytes + 2 * w_bytes + vb_bytes + wv_bytes; // 36.4 MB
  if (r0 < m_bytes) r0 = m_bytes;
  char* p = ws + r0;
  _Float16* qf = (_Float16*)p; p += qk_bytes;
  _Float16* kf = (_Float16*)p; p += qk_bytes;
  unsigned short* vT = (unsigned short*)p; p += vb_bytes;
  float* msumb       = (float*)p;

  convert2_f16_kernel<<<dim3((int)(w_elems / 2048), 2), 256, 0, stream>>>(Wq, Wk, Wqf, Wkf);
  convert2_f16_kernel<<<dim3((int)(qk_elems / 2048), 2), 256, 0, stream>>>(q, k, Xq, Xk);
  proj_qk2_kernel<<<dim3(64, 6, 2), 256, 0, stream>>>(Xq, Xk, Wqf, Wkf, qf, kf);

  convert_bf16_kernel<<<dim3((int)(v_elems / 2048)), 256, 0, stream>>>(v, vb);
  convert_bf16_kernel<<<dim3((int)(wv_elems / 2048)), 256, 0, stream>>>(Wv, Wvb);
  proj_v128_kernel<<<dim3(64, 4), 256, 0, stream>>>(vb, Wvb, vT);

  // mask_prep overwrites region0 (Xq/Xk/W*/vb/Wvb are dead by now)
  mask_prep_kernel<<<dim3(B_ * N_), 256, 0, stream>>>(masks, mbf, msumb);
  attn_kernel<<<dim3(N_ / 128, H_, B_), 128, 0, stream>>>(qf, kf, vT, mbf, msumb, out);
}

// Round 16
// 214.908 us; speedup vs baseline: 1.2315x; 1.2315x over previous
//
#include <hip/hip_runtime.h>
#include <hip/hip_bf16.h>

#define B_ 4
#define N_ 2048
#define H_ 8
#define C_ 768
#define CV_ 512
#define DH_ 96
#define DV_ 64
// SCALE = 32^-0.5 = 2^-2.5 ; K2E = SCALE * log2(e) = 0.25503486...
#define K2E_ 0.2550348620270320f

using bf16x8 = __attribute__((ext_vector_type(8))) short;
using f16x8  = __attribute__((ext_vector_type(8))) _Float16;
using f32x4  = __attribute__((ext_vector_type(4))) float;
using u16x4  = __attribute__((ext_vector_type(4))) unsigned short;

__device__ __forceinline__ unsigned short f2bf(float f) {
  union { float f; unsigned u; } x; x.f = f;
  unsigned r = x.u + 0x7fffu + ((x.u >> 16) & 1u);
  return (unsigned short)(r >> 16);
}
__device__ __forceinline__ float bf2f(unsigned short b) {
  union { unsigned u; float f; } x; x.u = ((unsigned)b) << 16;
  return x.f;
}
__device__ __forceinline__ void gload16(const void* g, void* l) {
  __builtin_amdgcn_global_load_lds(
      (const __attribute__((address_space(1))) void*)g,
      (__attribute__((address_space(3))) void*)l, 16, 0, 0);
}

#define MFMA_BF(a,b,c) __builtin_amdgcn_mfma_f32_16x16x32_bf16((a),(b),(c),0,0,0)
#define MFMA_F16(a,b,c) __builtin_amdgcn_mfma_f32_16x16x32_f16((a),(b),(c),0,0,0)

// ---------------------------------------------------------------------------
// f32 -> fp16 conversion, two tensors (blockIdx.y selects). 8 elems/thread.
// ---------------------------------------------------------------------------
__global__ __launch_bounds__(256) void convert2_f16_kernel(
    const float* __restrict__ in0, const float* __restrict__ in1,
    _Float16* __restrict__ o0, _Float16* __restrict__ o1)
{
  const float* in = blockIdx.y ? in1 : in0;
  _Float16* out = blockIdx.y ? o1 : o0;
  const size_t i8 = ((size_t)blockIdx.x * 256 + threadIdx.x) * 8;
  float4 v0 = *(const float4*)(in + i8);
  float4 v1 = *(const float4*)(in + i8 + 4);
  f16x8 o;
  o[0] = (_Float16)v0.x; o[1] = (_Float16)v0.y;
  o[2] = (_Float16)v0.z; o[3] = (_Float16)v0.w;
  o[4] = (_Float16)v1.x; o[5] = (_Float16)v1.y;
  o[6] = (_Float16)v1.z; o[7] = (_Float16)v1.w;
  *(f16x8*)(out + i8) = o;
}

// ---------------------------------------------------------------------------
// f32 -> bf16 conversion. 8 elems/thread.
// ---------------------------------------------------------------------------
__global__ __launch_bounds__(256) void convert_bf16_kernel(
    const float* __restrict__ in, unsigned short* __restrict__ out)
{
  const size_t i8 = ((size_t)blockIdx.x * 256 + threadIdx.x) * 8;
  float4 v0 = *(const float4*)(in + i8);
  float4 v1 = *(const float4*)(in + i8 + 4);
  u16x4 a, b;
  a[0] = f2bf(v0.x); a[1] = f2bf(v0.y); a[2] = f2bf(v0.z); a[3] = f2bf(v0.w);
  b[0] = f2bf(v1.x); b[1] = f2bf(v1.y); b[2] = f2bf(v1.z); b[3] = f2bf(v1.w);
  *(u16x4*)(out + i8) = a;
  *(u16x4*)(out + i8 + 4) = b;
}

// ---------------------------------------------------------------------------
// fp16 GEMM for Q and K projections in one dispatch (blockIdx.z selects).
// O = scale * (X @ W^T). 128x128 tile, BK=64, global_load_lds, linear LDS.
// Output fp16 at [(b*8+h)*2048+n]*96+d.  Q gets scale=K2E.
// ---------------------------------------------------------------------------
__global__ __launch_bounds__(256) void proj_qk2_kernel(
    const _Float16* __restrict__ Xq, const _Float16* __restrict__ Xk,
    const _Float16* __restrict__ Wqf, const _Float16* __restrict__ Wkf,
    _Float16* __restrict__ Oq, _Float16* __restrict__ Ok)
{
  __shared__ __align__(16) _Float16 Ah[128 * 64];
  __shared__ __align__(16) _Float16 Bh[128 * 64];

  const int zq = blockIdx.z;
  const _Float16* X = zq ? Xk : Xq;
  const _Float16* W = zq ? Wkf : Wqf;
  _Float16* O = zq ? Ok : Oq;
  const float scale = zq ? 1.0f : K2E_;

  const int mb = blockIdx.x * 128, nb = blockIdx.y * 128;
  const int t = threadIdx.x, w = t >> 6, lane = t & 63;
  const int fr = lane & 15, g = lane >> 4;
  const int wr = w >> 1, wc = w & 1;

  int offA[4], offB[4];
  unsigned ldsB[4];
#pragma unroll
  for (int j = 0; j < 4; ++j) {
    int lin = ((w * 4 + j) << 10) + (lane << 4);
    int r = lin >> 7, ce = (lin & 127) >> 1;
    offA[j] = (mb + r) * C_ + ce;
    offB[j] = (nb + r) * C_ + ce;
    ldsB[j] = (unsigned)((w * 4 + j) << 10);
  }

  f32x4 acc[4][4];
#pragma unroll
  for (int m = 0; m < 4; ++m)
#pragma unroll
    for (int n = 0; n < 4; ++n) acc[m][n] = (f32x4){0.f, 0.f, 0.f, 0.f};

  for (int kt = 0; kt < C_ / 64; ++kt) {
    const int kb = kt * 64;
    __syncthreads();
#pragma unroll
    for (int j = 0; j < 4; ++j) {
      gload16(X + offA[j] + kb, (char*)Ah + ldsB[j]);
      gload16(W + offB[j] + kb, (char*)Bh + ldsB[j]);
    }
    __syncthreads();
#pragma unroll
    for (int s = 0; s < 2; ++s) {
      const int cbyte = s * 64 + g * 16;
      f16x8 ah[4], bh2[4];
#pragma unroll
      for (int m = 0; m < 4; ++m)
        ah[m] = *(const f16x8*)((const char*)Ah + (wr * 64 + m * 16 + fr) * 128 + cbyte);
#pragma unroll
      for (int n = 0; n < 4; ++n)
        bh2[n] = *(const f16x8*)((const char*)Bh + (wc * 64 + n * 16 + fr) * 128 + cbyte);
#pragma unroll
      for (int m = 0; m < 4; ++m)
#pragma unroll
        for (int n = 0; n < 4; ++n)
          acc[m][n] = MFMA_F16(ah[m], bh2[n], acc[m][n]);
    }
  }

#pragma unroll
  for (int m = 0; m < 4; ++m) {
    const int Mrow = mb + wr * 64 + m * 16 + g * 4;
#pragma unroll
    for (int n = 0; n < 4; ++n) {
      const int co = nb + wc * 64 + n * 16 + fr;
      const int h = co / DH_, d = co - h * DH_;
#pragma unroll
      for (int r = 0; r < 4; ++r) {
        const int M = Mrow + r;
        const int b = M >> 11, nn = M & (N_ - 1);
        O[((size_t)((b * H_ + h) * N_ + nn)) * DH_ + d] = (_Float16)(acc[m][n][r] * scale);
      }
    }
  }
}

// ---------------------------------------------------------------------------
// V projection, 128x128 tile bf16 (m97 structure), storing V^T:
// OvT[(b*8+h)*64 + d][n].  X:(8192,512) bf16, W:(512,512) bf16.
// ---------------------------------------------------------------------------
__global__ __launch_bounds__(256) void proj_v128_kernel(
    const unsigned short* __restrict__ X, const unsigned short* __restrict__ W,
    unsigned short* __restrict__ OvT)
{
  __shared__ __align__(16) unsigned short Ah[128 * 64];
  __shared__ __align__(16) unsigned short Bh[128 * 64];

  const int mb = blockIdx.x * 128, nb = blockIdx.y * 128;
  const int t = threadIdx.x, w = t >> 6, lane = t & 63;
  const int fr = lane & 15, g = lane >> 4;
  const int wr = w >> 1, wc = w & 1;

  int offA[4], offB[4];
  unsigned ldsB[4];
#pragma unroll
  for (int j = 0; j < 4; ++j) {
    int lin = ((w * 4 + j) << 10) + (lane << 4);
    int r = lin >> 7, ce = (lin & 127) >> 1;
    offA[j] = (mb + r) * CV_ + ce;
    offB[j] = (nb + r) * CV_ + ce;
    ldsB[j] = (unsigned)((w * 4 + j) << 10);
  }

  f32x4 acc[4][4];
#pragma unroll
  for (int m = 0; m < 4; ++m)
#pragma unroll
    for (int n = 0; n < 4; ++n) acc[m][n] = (f32x4){0.f, 0.f, 0.f, 0.f};

  for (int kt = 0; kt < CV_ / 64; ++kt) {
    const int kb = kt * 64;
    __syncthreads();
#pragma unroll
    for (int j = 0; j < 4; ++j) {
      gload16(X + offA[j] + kb, (char*)Ah + ldsB[j]);
      gload16(W + offB[j] + kb, (char*)Bh + ldsB[j]);
    }
    __syncthreads();
#pragma unroll
    for (int s = 0; s < 2; ++s) {
      const int cbyte = s * 64 + g * 16;
      bf16x8 ah[4], bh2[4];
#pragma unroll
      for (int m = 0; m < 4; ++m)
        ah[m] = *(const bf16x8*)((const char*)Ah + (wr * 64 + m * 16 + fr) * 128 + cbyte);
#pragma unroll
      for (int n = 0; n < 4; ++n)
        bh2[n] = *(const bf16x8*)((const char*)Bh + (wc * 64 + n * 16 + fr) * 128 + cbyte);
#pragma unroll
      for (int m = 0; m < 4; ++m)
#pragma unroll
        for (int n = 0; n < 4; ++n)
          acc[m][n] = MFMA_BF(ah[m], bh2[n], acc[m][n]);
    }
  }

  // V^T store: 4 consecutive n per lane -> one b64 store
#pragma unroll
  for (int m = 0; m < 4; ++m) {
    const int M0 = mb + wr * 64 + m * 16 + g * 4;
    const int b = M0 >> 11, nn = M0 & (N_ - 1);
#pragma unroll
    for (int n = 0; n < 4; ++n) {
      const int co = nb + wc * 64 + n * 16 + fr;
      const int h = co >> 6, d = co & 63;
      u16x4 pk;
#pragma unroll
      for (int r = 0; r < 4; ++r) pk[r] = f2bf(acc[m][n][r]);
      *(u16x4*)(OvT + ((size_t)((b * H_ + h) * DV_ + d)) * N_ + nn) = pk;
    }
  }
}

// ---------------------------------------------------------------------------
// Mask pre-pass: bf16 copy + per-row sum. One block per (b,n) row.
// ---------------------------------------------------------------------------
__global__ __launch_bounds__(256) void mask_prep_kernel(
    const float* __restrict__ masks, unsigned short* __restrict__ mask_bf,
    float* __restrict__ msum)
{
  const int row = blockIdx.x;
  const int t = threadIdx.x;
  const float* p = masks + (size_t)row * N_;
  unsigned short* o = mask_bf + (size_t)row * N_;
  float4 v0 = *(const float4*)(p + t * 8);
  float4 v1 = *(const float4*)(p + t * 8 + 4);
  float s = v0.x + v0.y + v0.z + v0.w + v1.x + v1.y + v1.z + v1.w;
  u16x4 a, b;
  a[0] = f2bf(v0.x); a[1] = f2bf(v0.y); a[2] = f2bf(v0.z); a[3] = f2bf(v0.w);
  b[0] = f2bf(v1.x); b[1] = f2bf(v1.y); b[2] = f2bf(v1.z); b[3] = f2bf(v1.w);
  *(u16x4*)(o + t * 8) = a;
  *(u16x4*)(o + t * 8 + 4) = b;
#pragma unroll
  for (int ofs = 32; ofs > 0; ofs >>= 1) s += __shfl_down(s, ofs, 64);
  __shared__ float ws4[4];
  if ((t & 63) == 0) ws4[t >> 6] = s;
  __syncthreads();
  if (t == 0) msum[row] = ws4[0] + ws4[1] + ws4[2] + ws4[3];
}

// ---------------------------------------------------------------------------
// Attention: block = (qtile, h, b), 512 threads = 8 waves x 32 q-rows,
// QBLK=256. Each K/V tile staged once serves 256 q-rows; kh/vb reads
// amortize over 2 q-frags. Q/K fp16, P/mask/V bf16. Q pre-scaled by K2E.
// ---------------------------------------------------------------------------
__global__ __launch_bounds__(512) void attn_kernel(
    const _Float16* __restrict__ Qf, const _Float16* __restrict__ Kf,
    const unsigned short* __restrict__ VT,  const unsigned short* __restrict__ mask_bf,
    const float* __restrict__ msum, float* __restrict__ out)
{
  __shared__ __align__(16) _Float16 Ks[64][100];
  __shared__ __align__(16) unsigned short Vs[64][68];    // V^T tile: [d][k]
  __shared__ __align__(16) unsigned short Ps[256][68];   // P: [q][k_local]

  const int qbase = blockIdx.x * 256;
  const int h = blockIdx.y, b = blockIdx.z;
  const int t = threadIdx.x;
  const int w = t >> 6, lane = t & 63;
  const int fr = lane & 15, g = lane >> 4;
  const int kof = g * 8;

  const size_t bh = (size_t)(b * H_ + h);
  const _Float16* Kf_p = Kf + bh * N_ * DH_;
  const unsigned short* VT_p = VT + bh * DV_ * N_;

  // Q fragments: 2 q-frags (16 rows each) per wave
  f16x8 qh[2][3];
  size_t mrow_base[2];
#pragma unroll
  for (int wq = 0; wq < 2; ++wq) {
    const int qrow = qbase + w * 32 + wq * 16 + fr;
    mrow_base[wq] = ((size_t)b * N_ + qrow) * N_;
#pragma unroll
    for (int s = 0; s < 3; ++s)
      qh[wq][s] = *(const f16x8*)(Qf + (bh * N_ + qrow) * DH_ + s * 32 + kof);
  }

  // staging: K 64x96 f16 = 768 16B chunks over 512 threads (t, +512 if t<256)
  //          V 64x64 bf16 = 512 chunks, one per thread.
  const int kr0 = t / 12,         kc0 = (t % 12) * 8;
  const int kr1 = (512 + t) / 12, kc1 = ((512 + t) % 12) * 8;
  const int vr = t >> 3, vc = (t & 7) * 8;
  const bool has2 = (t < 256);

  f16x8 pk0, pk1;
  bf16x8 pv;
  auto load_regs = [&](int kb) {
    pk0 = *(const f16x8*)(Kf_p + (size_t)(kb + kr0) * DH_ + kc0);
    if (has2) pk1 = *(const f16x8*)(Kf_p + (size_t)(kb + kr1) * DH_ + kc1);
    pv = *(const bf16x8*)(VT_p + (size_t)vr * N_ + kb + vc);
  };

  f32x4 oacc[2][4];
#pragma unroll
  for (int wq = 0; wq < 2; ++wq)
#pragma unroll
    for (int i = 0; i < 4; ++i) oacc[wq][i] = (f32x4){0.f, 0.f, 0.f, 0.f};
  float z[2] = {0.f, 0.f};

  load_regs(0);

  for (int kt = 0; kt < N_ / 64; ++kt) {
    const int kb = kt * 64;
    __syncthreads();
    *(f16x8*)&Ks[kr0][kc0] = pk0;
    if (has2) *(f16x8*)&Ks[kr1][kc1] = pk1;
    *(bf16x8*)&Vs[vr][vc] = pv;
    __syncthreads();

    if (kt + 1 < N_ / 64) load_regs(kb + 64);

    // mask loads early (b64 bf16x4), consumed after QK
    u16x4 mk[2][4];
#pragma unroll
    for (int wq = 0; wq < 2; ++wq)
#pragma unroll
      for (int a = 0; a < 4; ++a)
        mk[wq][a] = *(const u16x4*)(mask_bf + mrow_base[wq] + kb + a * 16 + g * 4);

    // QK^T + softmax one 16-k group (a) at a time; kh read once per (a,s)
    // feeds 2 q-frag MFMAs.
#pragma unroll
    for (int a = 0; a < 4; ++a) {
      f16x8 kh[3];
#pragma unroll
      for (int s = 0; s < 3; ++s)
        kh[s] = *(const f16x8*)&Ks[a * 16 + fr][s * 32 + kof];
      f32x4 sacc[2];
#pragma unroll
      for (int wq = 0; wq < 2; ++wq) sacc[wq] = (f32x4){0.f, 0.f, 0.f, 0.f};
#pragma unroll
      for (int s = 0; s < 3; ++s)
#pragma unroll
        for (int wq = 0; wq < 2; ++wq)
          sacc[wq] = MFMA_F16(kh[s], qh[wq][s], sacc[wq]);

      // P = exp2(S) (Q pre-scaled); Z += P; Ps = bf16(P*mask), packed cvt
#pragma unroll
      for (int wq = 0; wq < 2; ++wq) {
        float e0 = exp2f(sacc[wq][0]);
        float e1 = exp2f(sacc[wq][1]);
        float e2 = exp2f(sacc[wq][2]);
        float e3 = exp2f(sacc[wq][3]);
        z[wq] += (e0 + e1) + (e2 + e3);
        union { __hip_bfloat162 h; unsigned u; } c01, c23;
        c01.h = __float22bfloat162_rn(make_float2(e0 * bf2f(mk[wq][a][0]),
                                                  e1 * bf2f(mk[wq][a][1])));
        c23.h = __float22bfloat162_rn(make_float2(e2 * bf2f(mk[wq][a][2]),
                                                  e3 * bf2f(mk[wq][a][3])));
        *(uint2*)&Ps[w * 32 + wq * 16 + fr][a * 16 + g * 4] = make_uint2(c01.u, c23.u);
      }
    }

    // O += P V  (Ps rows wave-private; vb read once feeds 2 q-frags)
#pragma unroll
    for (int s2 = 0; s2 < 2; ++s2) {
      bf16x8 pa[2];
#pragma unroll
      for (int wq = 0; wq < 2; ++wq)
        pa[wq] = *(const bf16x8*)&Ps[w * 32 + wq * 16 + fr][s2 * 32 + kof];
#pragma unroll
      for (int dt = 0; dt < 4; ++dt) {
        bf16x8 vb = *(const bf16x8*)&Vs[dt * 16 + fr][s2 * 32 + kof];
#pragma unroll
        for (int wq = 0; wq < 2; ++wq)
          oacc[wq][dt] = MFMA_BF(pa[wq], vb, oacc[wq][dt]);
      }
    }
  }

  // Z: reduce across the 4 k-row groups (lanes fr, fr+16, fr+32, fr+48)
#pragma unroll
  for (int wq = 0; wq < 2; ++wq) {
    z[wq] += __shfl_xor(z[wq], 16, 64);
    z[wq] += __shfl_xor(z[wq], 32, 64);
  }

  // epilogue: output rows are q16 = g*4+r; Z lives at lane fr=q16
#pragma unroll
  for (int wq = 0; wq < 2; ++wq) {
#pragma unroll
    for (int r = 0; r < 4; ++r) {
      int q = qbase + w * 32 + wq * 16 + g * 4 + r;
      float Z = __shfl(z[wq], g * 4 + r, 64);
      float inv = 1.0f / (Z * 8.0f * msum[b * N_ + q]);
#pragma unroll
      for (int dt = 0; dt < 4; ++dt)
        out[((size_t)b * N_ + q) * CV_ + h * DV_ + dt * 16 + fr] = oacc[wq][dt][r] * inv;
    }
  }
}

// ---------------------------------------------------------------------------
extern "C" void kernel_launch(void* const* d_in, const int* in_sizes, int n_in,
                              void* d_out, int out_size, void* d_ws, size_t ws_size,
                              hipStream_t stream)
{
  (void)in_sizes; (void)n_in; (void)out_size; (void)ws_size;
  const float* q     = (const float*)d_in[0];
  const float* k     = (const float*)d_in[1];
  const float* v     = (const float*)d_in[2];
  const float* masks = (const float*)d_in[3];
  const float* Wq    = (const float*)d_in[4];
  const float* Wk    = (const float*)d_in[5];
  const float* Wv    = (const float*)d_in[6];
  float* out = (float*)d_out;

  char* ws = (char*)d_ws;
  const size_t qk_elems = (size_t)B_ * N_ * C_;        // 6,291,456
  const size_t w_elems  = (size_t)C_ * C_;             // 589,824
  const size_t v_elems  = (size_t)B_ * N_ * CV_;       // 4,194,304
  const size_t wv_elems = (size_t)CV_ * CV_;           // 262,144
  const size_t qk_bytes = qk_elems * 2;                // 12,582,912
  const size_t w_bytes  = w_elems * 2;                 // 1,179,648
  const size_t vb_bytes = v_elems * 2;                 // 8,388,608
  const size_t wv_bytes = wv_elems * 2;                // 524,288
  const size_t m_bytes  = (size_t)B_ * N_ * N_ * 2;    // 33,554,432

  // region0: proj-phase temporaries, later overwritten by mbf (mask_prep).
  unsigned short* mbf = (unsigned short*)ws;
  _Float16* Xq  = (_Float16*)ws;
  _Float16* Xk  = (_Float16*)(ws + qk_bytes);
  _Float16* Wqf = (_Float16*)(ws + 2 * qk_bytes);
  _Float16* Wkf = (_Float16*)(ws + 2 * qk_bytes + w_bytes);
  unsigned short* vb  = (unsigned short*)(ws + 2 * qk_bytes + 2 * w_bytes);
  unsigned short* Wvb = (unsigned short*)(ws + 2 * qk_bytes + 2 * w_bytes + vb_bytes);
  size_t r0 = 2 * qk_bytes + 2 * w_bytes + vb_bytes + wv_bytes; // 36.4 MB
  if (r0 < m_bytes) r0 = m_bytes;
  char* p = ws + r0;
  _Float16* qf = (_Float16*)p; p += qk_bytes;
  _Float16* kf = (_Float16*)p; p += qk_bytes;
  unsigned short* vT = (unsigned short*)p; p += vb_bytes;
  float* msumb       = (float*)p;

  convert2_f16_kernel<<<dim3((int)(w_elems / 2048), 2), 256, 0, stream>>>(Wq, Wk, Wqf, Wkf);
  convert2_f16_kernel<<<dim3((int)(qk_elems / 2048), 2), 256, 0, stream>>>(q, k, Xq, Xk);
  proj_qk2_kernel<<<dim3(64, 6, 2), 256, 0, stream>>>(Xq, Xk, Wqf, Wkf, qf, kf);

  convert_bf16_kernel<<<dim3((int)(v_elems / 2048)), 256, 0, stream>>>(v, vb);
  convert_bf16_kernel<<<dim3((int)(wv_elems / 2048)), 256, 0, stream>>>(Wv, Wvb);
  proj_v128_kernel<<<dim3(64, 4), 256, 0, stream>>>(vb, Wvb, vT);

  // mask_prep overwrites region0 (Xq/Xk/W*/vb/Wvb are dead by now)
  mask_prep_kernel<<<dim3(B_ * N_), 256, 0, stream>>>(masks, mbf, msumb);
  attn_kernel<<<dim3(N_ / 256, H_, B_), 512, 0, stream>>>(qf, kf, vT, mbf, msumb, out);
}

// Round 17
// 202.854 us; speedup vs baseline: 1.3046x; 1.0594x over previous
//
#include <hip/hip_runtime.h>
#include <hip/hip_bf16.h>

#define B_ 4
#define N_ 2048
#define H_ 8
#define C_ 768
#define CV_ 512
#define DH_ 96
#define DV_ 64
// SCALE = 32^-0.5 = 2^-2.5 ; K2E = SCALE * log2(e) = 0.25503486...
#define K2E_ 0.2550348620270320f

using bf16x8 = __attribute__((ext_vector_type(8))) short;
using f16x8  = __attribute__((ext_vector_type(8))) _Float16;
using f32x4  = __attribute__((ext_vector_type(4))) float;
using u16x4  = __attribute__((ext_vector_type(4))) unsigned short;

__device__ __forceinline__ unsigned short f2bf(float f) {
  union { float f; unsigned u; } x; x.f = f;
  unsigned r = x.u + 0x7fffu + ((x.u >> 16) & 1u);
  return (unsigned short)(r >> 16);
}
__device__ __forceinline__ float bf2f(unsigned short b) {
  union { unsigned u; float f; } x; x.u = ((unsigned)b) << 16;
  return x.f;
}
__device__ __forceinline__ void gload16(const void* g, void* l) {
  __builtin_amdgcn_global_load_lds(
      (const __attribute__((address_space(1))) void*)g,
      (__attribute__((address_space(3))) void*)l, 16, 0, 0);
}

#define MFMA_BF(a,b,c) __builtin_amdgcn_mfma_f32_16x16x32_bf16((a),(b),(c),0,0,0)
#define MFMA_F16(a,b,c) __builtin_amdgcn_mfma_f32_16x16x32_f16((a),(b),(c),0,0,0)

// ---------------------------------------------------------------------------
// f32 -> fp16 conversion, two tensors (blockIdx.y selects). 8 elems/thread.
// ---------------------------------------------------------------------------
__global__ __launch_bounds__(256) void convert2_f16_kernel(
    const float* __restrict__ in0, const float* __restrict__ in1,
    _Float16* __restrict__ o0, _Float16* __restrict__ o1)
{
  const float* in = blockIdx.y ? in1 : in0;
  _Float16* out = blockIdx.y ? o1 : o0;
  const size_t i8 = ((size_t)blockIdx.x * 256 + threadIdx.x) * 8;
  float4 v0 = *(const float4*)(in + i8);
  float4 v1 = *(const float4*)(in + i8 + 4);
  f16x8 o;
  o[0] = (_Float16)v0.x; o[1] = (_Float16)v0.y;
  o[2] = (_Float16)v0.z; o[3] = (_Float16)v0.w;
  o[4] = (_Float16)v1.x; o[5] = (_Float16)v1.y;
  o[6] = (_Float16)v1.z; o[7] = (_Float16)v1.w;
  *(f16x8*)(out + i8) = o;
}

// ---------------------------------------------------------------------------
// f32 -> bf16 conversion. 8 elems/thread.
// ---------------------------------------------------------------------------
__global__ __launch_bounds__(256) void convert_bf16_kernel(
    const float* __restrict__ in, unsigned short* __restrict__ out)
{
  const size_t i8 = ((size_t)blockIdx.x * 256 + threadIdx.x) * 8;
  float4 v0 = *(const float4*)(in + i8);
  float4 v1 = *(const float4*)(in + i8 + 4);
  u16x4 a, b;
  a[0] = f2bf(v0.x); a[1] = f2bf(v0.y); a[2] = f2bf(v0.z); a[3] = f2bf(v0.w);
  b[0] = f2bf(v1.x); b[1] = f2bf(v1.y); b[2] = f2bf(v1.z); b[3] = f2bf(v1.w);
  *(u16x4*)(out + i8) = a;
  *(u16x4*)(out + i8 + 4) = b;
}

// ---------------------------------------------------------------------------
// fp16 GEMM for Q and K projections in one dispatch (blockIdx.z selects).
// O = scale * (X @ W^T). 128x128 tile, BK=64, global_load_lds, linear LDS.
// Output fp16 at [(b*8+h)*2048+n]*96+d.  Q gets scale=K2E.
// ---------------------------------------------------------------------------
__global__ __launch_bounds__(256) void proj_qk2_kernel(
    const _Float16* __restrict__ Xq, const _Float16* __restrict__ Xk,
    const _Float16* __restrict__ Wqf, const _Float16* __restrict__ Wkf,
    _Float16* __restrict__ Oq, _Float16* __restrict__ Ok)
{
  __shared__ __align__(16) _Float16 Ah[128 * 64];
  __shared__ __align__(16) _Float16 Bh[128 * 64];

  const int zq = blockIdx.z;
  const _Float16* X = zq ? Xk : Xq;
  const _Float16* W = zq ? Wkf : Wqf;
  _Float16* O = zq ? Ok : Oq;
  const float scale = zq ? 1.0f : K2E_;

  const int mb = blockIdx.x * 128, nb = blockIdx.y * 128;
  const int t = threadIdx.x, w = t >> 6, lane = t & 63;
  const int fr = lane & 15, g = lane >> 4;
  const int wr = w >> 1, wc = w & 1;

  int offA[4], offB[4];
  unsigned ldsB[4];
#pragma unroll
  for (int j = 0; j < 4; ++j) {
    int lin = ((w * 4 + j) << 10) + (lane << 4);
    int r = lin >> 7, ce = (lin & 127) >> 1;
    offA[j] = (mb + r) * C_ + ce;
    offB[j] = (nb + r) * C_ + ce;
    ldsB[j] = (unsigned)((w * 4 + j) << 10);
  }

  f32x4 acc[4][4];
#pragma unroll
  for (int m = 0; m < 4; ++m)
#pragma unroll
    for (int n = 0; n < 4; ++n) acc[m][n] = (f32x4){0.f, 0.f, 0.f, 0.f};

  for (int kt = 0; kt < C_ / 64; ++kt) {
    const int kb = kt * 64;
    __syncthreads();
#pragma unroll
    for (int j = 0; j < 4; ++j) {
      gload16(X + offA[j] + kb, (char*)Ah + ldsB[j]);
      gload16(W + offB[j] + kb, (char*)Bh + ldsB[j]);
    }
    __syncthreads();
#pragma unroll
    for (int s = 0; s < 2; ++s) {
      const int cbyte = s * 64 + g * 16;
      f16x8 ah[4], bh2[4];
#pragma unroll
      for (int m = 0; m < 4; ++m)
        ah[m] = *(const f16x8*)((const char*)Ah + (wr * 64 + m * 16 + fr) * 128 + cbyte);
#pragma unroll
      for (int n = 0; n < 4; ++n)
        bh2[n] = *(const f16x8*)((const char*)Bh + (wc * 64 + n * 16 + fr) * 128 + cbyte);
#pragma unroll
      for (int m = 0; m < 4; ++m)
#pragma unroll
        for (int n = 0; n < 4; ++n)
          acc[m][n] = MFMA_F16(ah[m], bh2[n], acc[m][n]);
    }
  }

#pragma unroll
  for (int m = 0; m < 4; ++m) {
    const int Mrow = mb + wr * 64 + m * 16 + g * 4;
#pragma unroll
    for (int n = 0; n < 4; ++n) {
      const int co = nb + wc * 64 + n * 16 + fr;
      const int h = co / DH_, d = co - h * DH_;
#pragma unroll
      for (int r = 0; r < 4; ++r) {
        const int M = Mrow + r;
        const int b = M >> 11, nn = M & (N_ - 1);
        O[((size_t)((b * H_ + h) * N_ + nn)) * DH_ + d] = (_Float16)(acc[m][n][r] * scale);
      }
    }
  }
}

// ---------------------------------------------------------------------------
// V projection, 128x128 tile bf16 (m97 structure), storing V^T:
// OvT[(b*8+h)*64 + d][n].  X:(8192,512) bf16, W:(512,512) bf16.
// ---------------------------------------------------------------------------
__global__ __launch_bounds__(256) void proj_v128_kernel(
    const unsigned short* __restrict__ X, const unsigned short* __restrict__ W,
    unsigned short* __restrict__ OvT)
{
  __shared__ __align__(16) unsigned short Ah[128 * 64];
  __shared__ __align__(16) unsigned short Bh[128 * 64];

  const int mb = blockIdx.x * 128, nb = blockIdx.y * 128;
  const int t = threadIdx.x, w = t >> 6, lane = t & 63;
  const int fr = lane & 15, g = lane >> 4;
  const int wr = w >> 1, wc = w & 1;

  int offA[4], offB[4];
  unsigned ldsB[4];
#pragma unroll
  for (int j = 0; j < 4; ++j) {
    int lin = ((w * 4 + j) << 10) + (lane << 4);
    int r = lin >> 7, ce = (lin & 127) >> 1;
    offA[j] = (mb + r) * CV_ + ce;
    offB[j] = (nb + r) * CV_ + ce;
    ldsB[j] = (unsigned)((w * 4 + j) << 10);
  }

  f32x4 acc[4][4];
#pragma unroll
  for (int m = 0; m < 4; ++m)
#pragma unroll
    for (int n = 0; n < 4; ++n) acc[m][n] = (f32x4){0.f, 0.f, 0.f, 0.f};

  for (int kt = 0; kt < CV_ / 64; ++kt) {
    const int kb = kt * 64;
    __syncthreads();
#pragma unroll
    for (int j = 0; j < 4; ++j) {
      gload16(X + offA[j] + kb, (char*)Ah + ldsB[j]);
      gload16(W + offB[j] + kb, (char*)Bh + ldsB[j]);
    }
    __syncthreads();
#pragma unroll
    for (int s = 0; s < 2; ++s) {
      const int cbyte = s * 64 + g * 16;
      bf16x8 ah[4], bh2[4];
#pragma unroll
      for (int m = 0; m < 4; ++m)
        ah[m] = *(const bf16x8*)((const char*)Ah + (wr * 64 + m * 16 + fr) * 128 + cbyte);
#pragma unroll
      for (int n = 0; n < 4; ++n)
        bh2[n] = *(const bf16x8*)((const char*)Bh + (wc * 64 + n * 16 + fr) * 128 + cbyte);
#pragma unroll
      for (int m = 0; m < 4; ++m)
#pragma unroll
        for (int n = 0; n < 4; ++n)
          acc[m][n] = MFMA_BF(ah[m], bh2[n], acc[m][n]);
    }
  }

  // V^T store: 4 consecutive n per lane -> one b64 store
#pragma unroll
  for (int m = 0; m < 4; ++m) {
    const int M0 = mb + wr * 64 + m * 16 + g * 4;
    const int b = M0 >> 11, nn = M0 & (N_ - 1);
#pragma unroll
    for (int n = 0; n < 4; ++n) {
      const int co = nb + wc * 64 + n * 16 + fr;
      const int h = co >> 6, d = co & 63;
      u16x4 pk;
#pragma unroll
      for (int r = 0; r < 4; ++r) pk[r] = f2bf(acc[m][n][r]);
      *(u16x4*)(OvT + ((size_t)((b * H_ + h) * DV_ + d)) * N_ + nn) = pk;
    }
  }
}

// ---------------------------------------------------------------------------
// Mask pre-pass: bf16 copy + per-row sum. One block per (b,n) row.
// ---------------------------------------------------------------------------
__global__ __launch_bounds__(256) void mask_prep_kernel(
    const float* __restrict__ masks, unsigned short* __restrict__ mask_bf,
    float* __restrict__ msum)
{
  const int row = blockIdx.x;
  const int t = threadIdx.x;
  const float* p = masks + (size_t)row * N_;
  unsigned short* o = mask_bf + (size_t)row * N_;
  float4 v0 = *(const float4*)(p + t * 8);
  float4 v1 = *(const float4*)(p + t * 8 + 4);
  float s = v0.x + v0.y + v0.z + v0.w + v1.x + v1.y + v1.z + v1.w;
  u16x4 a, b;
  a[0] = f2bf(v0.x); a[1] = f2bf(v0.y); a[2] = f2bf(v0.z); a[3] = f2bf(v0.w);
  b[0] = f2bf(v1.x); b[1] = f2bf(v1.y); b[2] = f2bf(v1.z); b[3] = f2bf(v1.w);
  *(u16x4*)(o + t * 8) = a;
  *(u16x4*)(o + t * 8 + 4) = b;
#pragma unroll
  for (int ofs = 32; ofs > 0; ofs >>= 1) s += __shfl_down(s, ofs, 64);
  __shared__ float ws4[4];
  if ((t & 63) == 0) ws4[t >> 6] = s;
  __syncthreads();
  if (t == 0) msum[row] = ws4[0] + ws4[1] + ws4[2] + ws4[3];
}

// ---------------------------------------------------------------------------
// Attention: block = (qtile, h, b), 256 threads = 4 waves x 32 q-rows,
// QBLK=128, 512 blocks (2/CU). K/V LDS DOUBLE-BUFFERED: one barrier per
// tile; stage-write of t+1 overlaps compute of t. Q/K fp16, P/mask/V bf16.
// ---------------------------------------------------------------------------
__global__ __launch_bounds__(256) void attn_kernel(
    const _Float16* __restrict__ Qf, const _Float16* __restrict__ Kf,
    const unsigned short* __restrict__ VT,  const unsigned short* __restrict__ mask_bf,
    const float* __restrict__ msum, float* __restrict__ out)
{
  __shared__ __align__(16) _Float16 Ks[2][64][100];
  __shared__ __align__(16) unsigned short Vs[2][64][68];  // V^T tile: [d][k]
  __shared__ __align__(16) unsigned short Ps[128][68];    // P: [q][k_local]

  const int qbase = blockIdx.x * 128;
  const int h = blockIdx.y, b = blockIdx.z;
  const int t = threadIdx.x;
  const int w = t >> 6, lane = t & 63;
  const int fr = lane & 15, g = lane >> 4;
  const int kof = g * 8;
  const int NT = N_ / 64;

  const size_t bh = (size_t)(b * H_ + h);
  const _Float16* Kf_p = Kf + bh * N_ * DH_;
  const unsigned short* VT_p = VT + bh * DV_ * N_;

  f16x8 qh[2][3];
  size_t mrow_base[2];
#pragma unroll
  for (int wq = 0; wq < 2; ++wq) {
    const int qrow = qbase + w * 32 + wq * 16 + fr;
    mrow_base[wq] = ((size_t)b * N_ + qrow) * N_;
#pragma unroll
    for (int s = 0; s < 3; ++s)
      qh[wq][s] = *(const f16x8*)(Qf + (bh * N_ + qrow) * DH_ + s * 32 + kof);
  }

  // staging: K 64x96 f16 = 768 16B chunks / 256 thr = 3 each; V 512 = 2 each
  int kr[3], kc[3], vr[2], vc[2];
#pragma unroll
  for (int i = 0; i < 3; ++i) { int c = t + 256 * i; kr[i] = c / 12; kc[i] = (c % 12) * 8; }
#pragma unroll
  for (int i = 0; i < 2; ++i) { int c = t + 256 * i; vr[i] = c >> 3; vc[i] = (c & 7) * 8; }

  f16x8 pk[3];
  bf16x8 pv[2];
  auto load_regs = [&](int kb) {
#pragma unroll
    for (int i = 0; i < 3; ++i)
      pk[i] = *(const f16x8*)(Kf_p + (size_t)(kb + kr[i]) * DH_ + kc[i]);
#pragma unroll
    for (int i = 0; i < 2; ++i)
      pv[i] = *(const bf16x8*)(VT_p + (size_t)vr[i] * N_ + kb + vc[i]);
  };
  auto write_lds = [&](int buf) {
#pragma unroll
    for (int i = 0; i < 3; ++i) *(f16x8*)&Ks[buf][kr[i]][kc[i]] = pk[i];
#pragma unroll
    for (int i = 0; i < 2; ++i) *(bf16x8*)&Vs[buf][vr[i]][vc[i]] = pv[i];
  };

  f32x4 oacc[2][4];
#pragma unroll
  for (int wq = 0; wq < 2; ++wq)
#pragma unroll
    for (int i = 0; i < 4; ++i) oacc[wq][i] = (f32x4){0.f, 0.f, 0.f, 0.f};
  float z[2] = {0.f, 0.f};

  // prolog: buf0 <- tile0; regs <- tile1
  load_regs(0);
  write_lds(0);
  load_regs(64);
  __syncthreads();

  for (int kt = 0; kt < NT; ++kt) {
    const int kb = kt * 64;
    const int cur = kt & 1;

    // stage tile kt+1 into the other buffer (regs already hold it),
    // then issue global loads for tile kt+2 -- both overlap compute below.
    if (kt + 1 < NT) write_lds(cur ^ 1);
    if (kt + 2 < NT) load_regs(kb + 128);

    // mask loads early (b64 bf16x4), consumed after QK
    u16x4 mk[2][4];
#pragma unroll
    for (int wq = 0; wq < 2; ++wq)
#pragma unroll
      for (int a = 0; a < 4; ++a)
        mk[wq][a] = *(const u16x4*)(mask_bf + mrow_base[wq] + kb + a * 16 + g * 4);

    // S^T = K * Q^T (f16): lane holds q=fr, k rows a*16+g*4+r
    f32x4 sacc[2][4];
#pragma unroll
    for (int wq = 0; wq < 2; ++wq)
#pragma unroll
      for (int a = 0; a < 4; ++a) sacc[wq][a] = (f32x4){0.f, 0.f, 0.f, 0.f};
#pragma unroll
    for (int s = 0; s < 3; ++s) {
#pragma unroll
      for (int a = 0; a < 4; ++a) {
        f16x8 kh = *(const f16x8*)&Ks[cur][a * 16 + fr][s * 32 + kof];
#pragma unroll
        for (int wq = 0; wq < 2; ++wq)
          sacc[wq][a] = MFMA_F16(kh, qh[wq][s], sacc[wq][a]);
      }
    }

    // P = exp2(S) (Q pre-scaled); Z += P (tree); Ps = bf16(P*mask), packed cvt
#pragma unroll
    for (int wq = 0; wq < 2; ++wq) {
#pragma unroll
      for (int a = 0; a < 4; ++a) {
        float e0 = exp2f(sacc[wq][a][0]);
        float e1 = exp2f(sacc[wq][a][1]);
        float e2 = exp2f(sacc[wq][a][2]);
        float e3 = exp2f(sacc[wq][a][3]);
        z[wq] += (e0 + e1) + (e2 + e3);
        union { __hip_bfloat162 h; unsigned u; } c01, c23;
        c01.h = __float22bfloat162_rn(make_float2(e0 * bf2f(mk[wq][a][0]),
                                                  e1 * bf2f(mk[wq][a][1])));
        c23.h = __float22bfloat162_rn(make_float2(e2 * bf2f(mk[wq][a][2]),
                                                  e3 * bf2f(mk[wq][a][3])));
        *(uint2*)&Ps[w * 32 + wq * 16 + fr][a * 16 + g * 4] = make_uint2(c01.u, c23.u);
      }
    }

    // O += P V  (Ps rows are wave-private: no barrier needed)
#pragma unroll
    for (int s2 = 0; s2 < 2; ++s2) {
      bf16x8 pa[2];
#pragma unroll
      for (int wq = 0; wq < 2; ++wq)
        pa[wq] = *(const bf16x8*)&Ps[w * 32 + wq * 16 + fr][s2 * 32 + kof];
#pragma unroll
      for (int dt = 0; dt < 4; ++dt) {
        bf16x8 vb = *(const bf16x8*)&Vs[cur][dt * 16 + fr][s2 * 32 + kof];
#pragma unroll
        for (int wq = 0; wq < 2; ++wq)
          oacc[wq][dt] = MFMA_BF(pa[wq], vb, oacc[wq][dt]);
      }
    }

    // single barrier per tile: my reads of buf[cur] are done; my writes to
    // buf[cur^1] become visible for the next iteration.
    __syncthreads();
  }

  // Z: reduce across the 4 k-row groups (lanes fr, fr+16, fr+32, fr+48)
#pragma unroll
  for (int wq = 0; wq < 2; ++wq) {
    z[wq] += __shfl_xor(z[wq], 16, 64);
    z[wq] += __shfl_xor(z[wq], 32, 64);
  }

  // epilogue: output rows are q16 = g*4+r; Z lives at lane fr=q16
#pragma unroll
  for (int wq = 0; wq < 2; ++wq) {
#pragma unroll
    for (int r = 0; r < 4; ++r) {
      int q = qbase + w * 32 + wq * 16 + g * 4 + r;
      float Z = __shfl(z[wq], g * 4 + r, 64);
      float inv = 1.0f / (Z * 8.0f * msum[b * N_ + q]);
#pragma unroll
      for (int dt = 0; dt < 4; ++dt)
        out[((size_t)b * N_ + q) * CV_ + h * DV_ + dt * 16 + fr] = oacc[wq][dt][r] * inv;
    }
  }
}

// ---------------------------------------------------------------------------
extern "C" void kernel_launch(void* const* d_in, const int* in_sizes, int n_in,
                              void* d_out, int out_size, void* d_ws, size_t ws_size,
                              hipStream_t stream)
{
  (void)in_sizes; (void)n_in; (void)out_size; (void)ws_size;
  const float* q     = (const float*)d_in[0];
  const float* k     = (const float*)d_in[1];
  const float* v     = (const float*)d_in[2];
  const float* masks = (const float*)d_in[3];
  const float* Wq    = (const float*)d_in[4];
  const float* Wk    = (const float*)d_in[5];
  const float* Wv    = (const float*)d_in[6];
  float* out = (float*)d_out;

  char* ws = (char*)d_ws;
  const size_t qk_elems = (size_t)B_ * N_ * C_;        // 6,291,456
  const size_t w_elems  = (size_t)C_ * C_;             // 589,824
  const size_t v_elems  = (size_t)B_ * N_ * CV_;       // 4,194,304
  const size_t wv_elems = (size_t)CV_ * CV_;           // 262,144
  const size_t qk_bytes = qk_elems * 2;                // 12,582,912
  const size_t w_bytes  = w_elems * 2;                 // 1,179,648
  const size_t vb_bytes = v_elems * 2;                 // 8,388,608
  const size_t wv_bytes = wv_elems * 2;                // 524,288
  const size_t m_bytes  = (size_t)B_ * N_ * N_ * 2;    // 33,554,432

  // region0: proj-phase temporaries, later overwritten by mbf (mask_prep).
  unsigned short* mbf = (unsigned short*)ws;
  _Float16* Xq  = (_Float16*)ws;
  _Float16* Xk  = (_Float16*)(ws + qk_bytes);
  _Float16* Wqf = (_Float16*)(ws + 2 * qk_bytes);
  _Float16* Wkf = (_Float16*)(ws + 2 * qk_bytes + w_bytes);
  unsigned short* vb  = (unsigned short*)(ws + 2 * qk_bytes + 2 * w_bytes);
  unsigned short* Wvb = (unsigned short*)(ws + 2 * qk_bytes + 2 * w_bytes + vb_bytes);
  size_t r0 = 2 * qk_bytes + 2 * w_bytes + vb_bytes + wv_bytes; // 36.4 MB
  if (r0 < m_bytes) r0 = m_bytes;
  char* p = ws + r0;
  _Float16* qf = (_Float16*)p; p += qk_bytes;
  _Float16* kf = (_Float16*)p; p += qk_bytes;
  unsigned short* vT = (unsigned short*)p; p += vb_bytes;
  float* msumb       = (float*)p;

  convert2_f16_kernel<<<dim3((int)(w_elems / 2048), 2), 256, 0, stream>>>(Wq, Wk, Wqf, Wkf);
  convert2_f16_kernel<<<dim3((int)(qk_elems / 2048), 2), 256, 0, stream>>>(q, k, Xq, Xk);
  proj_qk2_kernel<<<dim3(64, 6, 2), 256, 0, stream>>>(Xq, Xk, Wqf, Wkf, qf, kf);

  convert_bf16_kernel<<<dim3((int)(v_elems / 2048)), 256, 0, stream>>>(v, vb);
  convert_bf16_kernel<<<dim3((int)(wv_elems / 2048)), 256, 0, stream>>>(Wv, Wvb);
  proj_v128_kernel<<<dim3(64, 4), 256, 0, stream>>>(vb, Wvb, vT);

  // mask_prep overwrites region0 (Xq/Xk/W*/vb/Wvb are dead by now)
  mask_prep_kernel<<<dim3(B_ * N_), 256, 0, stream>>>(masks, mbf, msumb);
  attn_kernel<<<dim3(N_ / 128, H_, B_), 256, 0, stream>>>(qf, kf, vT, mbf, msumb, out);
}

// Round 19
// 183.895 us; speedup vs baseline: 1.4391x; 1.1031x over previous
//
#include <hip/hip_runtime.h>
#include <hip/hip_bf16.h>

#define B_ 4
#define N_ 2048
#define H_ 8
#define C_ 768
#define CV_ 512
#define DH_ 96
#define DV_ 64
// SCALE = 32^-0.5 = 2^-2.5 ; K2E = SCALE * log2(e) = 0.25503486...
#define K2E_ 0.2550348620270320f

using bf16x8 = __attribute__((ext_vector_type(8))) short;
using f16x8  = __attribute__((ext_vector_type(8))) _Float16;
using f32x4  = __attribute__((ext_vector_type(4))) float;
using u16x4  = __attribute__((ext_vector_type(4))) unsigned short;

__device__ __forceinline__ unsigned short f2bf(float f) {
  union { float f; unsigned u; } x; x.f = f;
  unsigned r = x.u + 0x7fffu + ((x.u >> 16) & 1u);
  return (unsigned short)(r >> 16);
}
__device__ __forceinline__ float bf2f(unsigned short b) {
  union { unsigned u; float f; } x; x.u = ((unsigned)b) << 16;
  return x.f;
}
__device__ __forceinline__ void gload16(const void* g, void* l) {
  __builtin_amdgcn_global_load_lds(
      (const __attribute__((address_space(1))) void*)g,
      (__attribute__((address_space(3))) void*)l, 16, 0, 0);
}

#define MFMA_BF(a,b,c) __builtin_amdgcn_mfma_f32_16x16x32_bf16((a),(b),(c),0,0,0)
#define MFMA_F16(a,b,c) __builtin_amdgcn_mfma_f32_16x16x32_f16((a),(b),(c),0,0,0)

// ---------------------------------------------------------------------------
// f32 -> fp16 conversion, two tensors (blockIdx.y selects). 8 elems/thread.
// ---------------------------------------------------------------------------
__global__ __launch_bounds__(256) void convert2_f16_kernel(
    const float* __restrict__ in0, const float* __restrict__ in1,
    _Float16* __restrict__ o0, _Float16* __restrict__ o1)
{
  const float* in = blockIdx.y ? in1 : in0;
  _Float16* out = blockIdx.y ? o1 : o0;
  const size_t i8 = ((size_t)blockIdx.x * 256 + threadIdx.x) * 8;
  float4 v0 = *(const float4*)(in + i8);
  float4 v1 = *(const float4*)(in + i8 + 4);
  f16x8 o;
  o[0] = (_Float16)v0.x; o[1] = (_Float16)v0.y;
  o[2] = (_Float16)v0.z; o[3] = (_Float16)v0.w;
  o[4] = (_Float16)v1.x; o[5] = (_Float16)v1.y;
  o[6] = (_Float16)v1.z; o[7] = (_Float16)v1.w;
  *(f16x8*)(out + i8) = o;
}

// ---------------------------------------------------------------------------
// f32 -> bf16 conversion. 8 elems/thread.
// ---------------------------------------------------------------------------
__global__ __launch_bounds__(256) void convert_bf16_kernel(
    const float* __restrict__ in, unsigned short* __restrict__ out)
{
  const size_t i8 = ((size_t)blockIdx.x * 256 + threadIdx.x) * 8;
  float4 v0 = *(const float4*)(in + i8);
  float4 v1 = *(const float4*)(in + i8 + 4);
  u16x4 a, b;
  a[0] = f2bf(v0.x); a[1] = f2bf(v0.y); a[2] = f2bf(v0.z); a[3] = f2bf(v0.w);
  b[0] = f2bf(v1.x); b[1] = f2bf(v1.y); b[2] = f2bf(v1.z); b[3] = f2bf(v1.w);
  *(u16x4*)(out + i8) = a;
  *(u16x4*)(out + i8 + 4) = b;
}

// ---------------------------------------------------------------------------
// fp16 GEMM for Q and K projections in one dispatch (blockIdx.z selects).
// O = scale * (X @ W^T). 128x128 tile, BK=64, global_load_lds, linear LDS.
// Output fp16 at [(b*8+h)*2048+n]*96+d.  Q gets scale=K2E.
// ---------------------------------------------------------------------------
__global__ __launch_bounds__(256) void proj_qk2_kernel(
    const _Float16* __restrict__ Xq, const _Float16* __restrict__ Xk,
    const _Float16* __restrict__ Wqf, const _Float16* __restrict__ Wkf,
    _Float16* __restrict__ Oq, _Float16* __restrict__ Ok)
{
  __shared__ __align__(16) _Float16 Ah[128 * 64];
  __shared__ __align__(16) _Float16 Bh[128 * 64];

  const int zq = blockIdx.z;
  const _Float16* X = zq ? Xk : Xq;
  const _Float16* W = zq ? Wkf : Wqf;
  _Float16* O = zq ? Ok : Oq;
  const float scale = zq ? 1.0f : K2E_;

  const int mb = blockIdx.x * 128, nb = blockIdx.y * 128;
  const int t = threadIdx.x, w = t >> 6, lane = t & 63;
  const int fr = lane & 15, g = lane >> 4;
  const int wr = w >> 1, wc = w & 1;

  int offA[4], offB[4];
  unsigned ldsB[4];
#pragma unroll
  for (int j = 0; j < 4; ++j) {
    int lin = ((w * 4 + j) << 10) + (lane << 4);
    int r = lin >> 7, ce = (lin & 127) >> 1;
    offA[j] = (mb + r) * C_ + ce;
    offB[j] = (nb + r) * C_ + ce;
    ldsB[j] = (unsigned)((w * 4 + j) << 10);
  }

  f32x4 acc[4][4];
#pragma unroll
  for (int m = 0; m < 4; ++m)
#pragma unroll
    for (int n = 0; n < 4; ++n) acc[m][n] = (f32x4){0.f, 0.f, 0.f, 0.f};

  for (int kt = 0; kt < C_ / 64; ++kt) {
    const int kb = kt * 64;
    __syncthreads();
#pragma unroll
    for (int j = 0; j < 4; ++j) {
      gload16(X + offA[j] + kb, (char*)Ah + ldsB[j]);
      gload16(W + offB[j] + kb, (char*)Bh + ldsB[j]);
    }
    __syncthreads();
#pragma unroll
    for (int s = 0; s < 2; ++s) {
      const int cbyte = s * 64 + g * 16;
      f16x8 ah[4], bh2[4];
#pragma unroll
      for (int m = 0; m < 4; ++m)
        ah[m] = *(const f16x8*)((const char*)Ah + (wr * 64 + m * 16 + fr) * 128 + cbyte);
#pragma unroll
      for (int n = 0; n < 4; ++n)
        bh2[n] = *(const f16x8*)((const char*)Bh + (wc * 64 + n * 16 + fr) * 128 + cbyte);
#pragma unroll
      for (int m = 0; m < 4; ++m)
#pragma unroll
        for (int n = 0; n < 4; ++n)
          acc[m][n] = MFMA_F16(ah[m], bh2[n], acc[m][n]);
    }
  }

#pragma unroll
  for (int m = 0; m < 4; ++m) {
    const int Mrow = mb + wr * 64 + m * 16 + g * 4;
#pragma unroll
    for (int n = 0; n < 4; ++n) {
      const int co = nb + wc * 64 + n * 16 + fr;
      const int h = co / DH_, d = co - h * DH_;
#pragma unroll
      for (int r = 0; r < 4; ++r) {
        const int M = Mrow + r;
        const int b = M >> 11, nn = M & (N_ - 1);
        O[((size_t)((b * H_ + h) * N_ + nn)) * DH_ + d] = (_Float16)(acc[m][n][r] * scale);
      }
    }
  }
}

// ---------------------------------------------------------------------------
// V projection, 128x128 tile bf16 (m97 structure), storing V^T:
// OvT[(b*8+h)*64 + d][n].  X:(8192,512) bf16, W:(512,512) bf16.
// ---------------------------------------------------------------------------
__global__ __launch_bounds__(256) void proj_v128_kernel(
    const unsigned short* __restrict__ X, const unsigned short* __restrict__ W,
    unsigned short* __restrict__ OvT)
{
  __shared__ __align__(16) unsigned short Ah[128 * 64];
  __shared__ __align__(16) unsigned short Bh[128 * 64];

  const int mb = blockIdx.x * 128, nb = blockIdx.y * 128;
  const int t = threadIdx.x, w = t >> 6, lane = t & 63;
  const int fr = lane & 15, g = lane >> 4;
  const int wr = w >> 1, wc = w & 1;

  int offA[4], offB[4];
  unsigned ldsB[4];
#pragma unroll
  for (int j = 0; j < 4; ++j) {
    int lin = ((w * 4 + j) << 10) + (lane << 4);
    int r = lin >> 7, ce = (lin & 127) >> 1;
    offA[j] = (mb + r) * CV_ + ce;
    offB[j] = (nb + r) * CV_ + ce;
    ldsB[j] = (unsigned)((w * 4 + j) << 10);
  }

  f32x4 acc[4][4];
#pragma unroll
  for (int m = 0; m < 4; ++m)
#pragma unroll
    for (int n = 0; n < 4; ++n) acc[m][n] = (f32x4){0.f, 0.f, 0.f, 0.f};

  for (int kt = 0; kt < CV_ / 64; ++kt) {
    const int kb = kt * 64;
    __syncthreads();
#pragma unroll
    for (int j = 0; j < 4; ++j) {
      gload16(X + offA[j] + kb, (char*)Ah + ldsB[j]);
      gload16(W + offB[j] + kb, (char*)Bh + ldsB[j]);
    }
    __syncthreads();
#pragma unroll
    for (int s = 0; s < 2; ++s) {
      const int cbyte = s * 64 + g * 16;
      bf16x8 ah[4], bh2[4];
#pragma unroll
      for (int m = 0; m < 4; ++m)
        ah[m] = *(const bf16x8*)((const char*)Ah + (wr * 64 + m * 16 + fr) * 128 + cbyte);
#pragma unroll
      for (int n = 0; n < 4; ++n)
        bh2[n] = *(const bf16x8*)((const char*)Bh + (wc * 64 + n * 16 + fr) * 128 + cbyte);
#pragma unroll
      for (int m = 0; m < 4; ++m)
#pragma unroll
        for (int n = 0; n < 4; ++n)
          acc[m][n] = MFMA_BF(ah[m], bh2[n], acc[m][n]);
    }
  }

  // V^T store: 4 consecutive n per lane -> one b64 store
#pragma unroll
  for (int m = 0; m < 4; ++m) {
    const int M0 = mb + wr * 64 + m * 16 + g * 4;
    const int b = M0 >> 11, nn = M0 & (N_ - 1);
#pragma unroll
    for (int n = 0; n < 4; ++n) {
      const int co = nb + wc * 64 + n * 16 + fr;
      const int h = co >> 6, d = co & 63;
      u16x4 pk;
#pragma unroll
      for (int r = 0; r < 4; ++r) pk[r] = f2bf(acc[m][n][r]);
      *(u16x4*)(OvT + ((size_t)((b * H_ + h) * DV_ + d)) * N_ + nn) = pk;
    }
  }
}

// ---------------------------------------------------------------------------
// Mask pre-pass: bf16 copy + per-row sum. One block per (b,n) row.
// ---------------------------------------------------------------------------
__global__ __launch_bounds__(256) void mask_prep_kernel(
    const float* __restrict__ masks, unsigned short* __restrict__ mask_bf,
    float* __restrict__ msum)
{
  const int row = blockIdx.x;
  const int t = threadIdx.x;
  const float* p = masks + (size_t)row * N_;
  unsigned short* o = mask_bf + (size_t)row * N_;
  float4 v0 = *(const float4*)(p + t * 8);
  float4 v1 = *(const float4*)(p + t * 8 + 4);
  float s = v0.x + v0.y + v0.z + v0.w + v1.x + v1.y + v1.z + v1.w;
  u16x4 a, b;
  a[0] = f2bf(v0.x); a[1] = f2bf(v0.y); a[2] = f2bf(v0.z); a[3] = f2bf(v0.w);
  b[0] = f2bf(v1.x); b[1] = f2bf(v1.y); b[2] = f2bf(v1.z); b[3] = f2bf(v1.w);
  *(u16x4*)(o + t * 8) = a;
  *(u16x4*)(o + t * 8 + 4) = b;
#pragma unroll
  for (int ofs = 32; ofs > 0; ofs >>= 1) s += __shfl_down(s, ofs, 64);
  __shared__ float ws4[4];
  if ((t & 63) == 0) ws4[t >> 6] = s;
  __syncthreads();
  if (t == 0) msum[row] = ws4[0] + ws4[1] + ws4[2] + ws4[3];
}

// ---------------------------------------------------------------------------
// Attention: block = (qtile, h, b), 512 threads = 8 waves x 16 q-rows.
// Same QBLK=128 and LDS as before, but 2x waves share the staging ->
// 16 waves/CU (4/SIMD) instead of 8 (2/SIMD). Q/K fp16, P/mask/V bf16.
// ---------------------------------------------------------------------------
__global__ __launch_bounds__(512, 4) void attn_kernel(
    const _Float16* __restrict__ Qf, const _Float16* __restrict__ Kf,
    const unsigned short* __restrict__ VT,  const unsigned short* __restrict__ mask_bf,
    const float* __restrict__ msum, float* __restrict__ out)
{
  __shared__ __align__(16) _Float16 Ks[64][100];
  __shared__ __align__(16) unsigned short Vs[64][68];    // V^T tile: [d][k]
  __shared__ __align__(16) unsigned short Ps[128][68];   // P: [q][k_local]

  const int qbase = blockIdx.x * 128;
  const int h = blockIdx.y, b = blockIdx.z;
  const int t = threadIdx.x;
  const int w = t >> 6, lane = t & 63;
  const int fr = lane & 15, g = lane >> 4;
  const int kof = g * 8;

  const size_t bh = (size_t)(b * H_ + h);
  const _Float16* Kf_p = Kf + bh * N_ * DH_;
  const unsigned short* VT_p = VT + bh * DV_ * N_;

  const int qrow = qbase + w * 16 + fr;
  const size_t mrow_base = ((size_t)b * N_ + qrow) * N_;

  f16x8 qh[3];
#pragma unroll
  for (int s = 0; s < 3; ++s)
    qh[s] = *(const f16x8*)(Qf + (bh * N_ + qrow) * DH_ + s * 32 + kof);

  // K tile: 64x96 f16 = 768 b128 chunks over 512 threads (t, and 512+t for t<256)
  // V tile: 64x64 bf16 = 512 chunks, one per thread.
  const int kr0 = t / 12,         kc0 = (t % 12) * 8;
  const int kr1 = (512 + t) / 12, kc1 = ((512 + t) % 12) * 8;
  const int vr = t >> 3, vc = (t & 7) * 8;
  const bool has2 = (t < 256);

  f16x8 pk0, pk1;
  bf16x8 pv;
  auto load_regs = [&](int kb) {
    pk0 = *(const f16x8*)(Kf_p + (size_t)(kb + kr0) * DH_ + kc0);
    if (has2) pk1 = *(const f16x8*)(Kf_p + (size_t)(kb + kr1) * DH_ + kc1);
    pv = *(const bf16x8*)(VT_p + (size_t)vr * N_ + kb + vc);
  };

  f32x4 oacc[4];
#pragma unroll
  for (int i = 0; i < 4; ++i) oacc[i] = (f32x4){0.f, 0.f, 0.f, 0.f};
  float z = 0.f;

  load_regs(0);

  for (int kt = 0; kt < N_ / 64; ++kt) {
    const int kb = kt * 64;
    __syncthreads();
    *(f16x8*)&Ks[kr0][kc0] = pk0;
    if (has2) *(f16x8*)&Ks[kr1][kc1] = pk1;
    *(bf16x8*)&Vs[vr][vc] = pv;
    __syncthreads();

    if (kt + 1 < N_ / 64) load_regs(kb + 64);

    // mask loads early (b64 bf16x4), consumed after QK
    u16x4 mk[4];
#pragma unroll
    for (int a = 0; a < 4; ++a)
      mk[a] = *(const u16x4*)(mask_bf + mrow_base + kb + a * 16 + g * 4);

    // S^T = K * Q^T (f16): lane holds q=fr, k rows a*16+g*4+r
    f32x4 sacc[4];
#pragma unroll
    for (int a = 0; a < 4; ++a) sacc[a] = (f32x4){0.f, 0.f, 0.f, 0.f};
#pragma unroll
    for (int s = 0; s < 3; ++s) {
#pragma unroll
      for (int a = 0; a < 4; ++a) {
        f16x8 kh = *(const f16x8*)&Ks[a * 16 + fr][s * 32 + kof];
        sacc[a] = MFMA_F16(kh, qh[s], sacc[a]);
      }
    }

    // P = exp2(S) (Q pre-scaled); Z += P (tree); Ps = bf16(P*mask), packed cvt
#pragma unroll
    for (int a = 0; a < 4; ++a) {
      float e0 = exp2f(sacc[a][0]);
      float e1 = exp2f(sacc[a][1]);
      float e2 = exp2f(sacc[a][2]);
      float e3 = exp2f(sacc[a][3]);
      z += (e0 + e1) + (e2 + e3);
      union { __hip_bfloat162 h; unsigned u; } c01, c23;
      c01.h = __float22bfloat162_rn(make_float2(e0 * bf2f(mk[a][0]),
                                                e1 * bf2f(mk[a][1])));
      c23.h = __float22bfloat162_rn(make_float2(e2 * bf2f(mk[a][2]),
                                                e3 * bf2f(mk[a][3])));
      *(uint2*)&Ps[w * 16 + fr][a * 16 + g * 4] = make_uint2(c01.u, c23.u);
    }

    // O += P V  (Ps rows are wave-private: no barrier needed)
#pragma unroll
    for (int s2 = 0; s2 < 2; ++s2) {
      bf16x8 pa = *(const bf16x8*)&Ps[w * 16 + fr][s2 * 32 + kof];
#pragma unroll
      for (int dt = 0; dt < 4; ++dt) {
        bf16x8 vb = *(const bf16x8*)&Vs[dt * 16 + fr][s2 * 32 + kof];
        oacc[dt] = MFMA_BF(pa, vb, oacc[dt]);
      }
    }
  }

  // Z: reduce across the 4 k-row groups (lanes fr, fr+16, fr+32, fr+48)
  z += __shfl_xor(z, 16, 64);
  z += __shfl_xor(z, 32, 64);

  // epilogue: output rows are q16 = g*4+r; Z lives at lane fr=q16
#pragma unroll
  for (int r = 0; r < 4; ++r) {
    int q = qbase + w * 16 + g * 4 + r;
    float Z = __shfl(z, g * 4 + r, 64);
    float inv = 1.0f / (Z * 8.0f * msum[b * N_ + q]);
#pragma unroll
    for (int dt = 0; dt < 4; ++dt)
      out[((size_t)b * N_ + q) * CV_ + h * DV_ + dt * 16 + fr] = oacc[dt][r] * inv;
  }
}

// ---------------------------------------------------------------------------
extern "C" void kernel_launch(void* const* d_in, const int* in_sizes, int n_in,
                              void* d_out, int out_size, void* d_ws, size_t ws_size,
                              hipStream_t stream)
{
  (void)in_sizes; (void)n_in; (void)out_size; (void)ws_size;
  const float* q     = (const float*)d_in[0];
  const float* k     = (const float*)d_in[1];
  const float* v     = (const float*)d_in[2];
  const float* masks = (const float*)d_in[3];
  const float* Wq    = (const float*)d_in[4];
  const float* Wk    = (const float*)d_in[5];
  const float* Wv    = (const float*)d_in[6];
  float* out = (float*)d_out;

  char* ws = (char*)d_ws;
  const size_t qk_elems = (size_t)B_ * N_ * C_;        // 6,291,456
  const size_t w_elems  = (size_t)C_ * C_;             // 589,824
  const size_t v_elems  = (size_t)B_ * N_ * CV_;       // 4,194,304
  const size_t wv_elems = (size_t)CV_ * CV_;           // 262,144
  const size_t qk_bytes = qk_elems * 2;                // 12,582,912
  const size_t w_bytes  = w_elems * 2;                 // 1,179,648
  const size_t vb_bytes = v_elems * 2;                 // 8,388,608
  const size_t wv_bytes = wv_elems * 2;                // 524,288
  const size_t m_bytes  = (size_t)B_ * N_ * N_ * 2;    // 33,554,432

  // region0: proj-phase temporaries, later overwritten by mbf (mask_prep).
  unsigned short* mbf = (unsigned short*)ws;
  _Float16* Xq  = (_Float16*)ws;
  _Float16* Xk  = (_Float16*)(ws + qk_bytes);
  _Float16* Wqf = (_Float16*)(ws + 2 * qk_bytes);
  _Float16* Wkf = (_Float16*)(ws + 2 * qk_bytes + w_bytes);
  unsigned short* vb  = (unsigned short*)(ws + 2 * qk_bytes + 2 * w_bytes);
  unsigned short* Wvb = (unsigned short*)(ws + 2 * qk_bytes + 2 * w_bytes + vb_bytes);
  size_t r0 = 2 * qk_bytes + 2 * w_bytes + vb_bytes + wv_bytes; // 36.4 MB
  if (r0 < m_bytes) r0 = m_bytes;
  char* p = ws + r0;
  _Float16* qf = (_Float16*)p; p += qk_bytes;
  _Float16* kf = (_Float16*)p; p += qk_bytes;
  unsigned short* vT = (unsigned short*)p; p += vb_bytes;
  float* msumb       = (float*)p;

  convert2_f16_kernel<<<dim3((int)(w_elems / 2048), 2), 256, 0, stream>>>(Wq, Wk, Wqf, Wkf);
  convert2_f16_kernel<<<dim3((int)(qk_elems / 2048), 2), 256, 0, stream>>>(q, k, Xq, Xk);
  proj_qk2_kernel<<<dim3(64, 6, 2), 256, 0, stream>>>(Xq, Xk, Wqf, Wkf, qf, kf);

  convert_bf16_kernel<<<dim3((int)(v_elems / 2048)), 256, 0, stream>>>(v, vb);
  convert_bf16_kernel<<<dim3((int)(wv_elems / 2048)), 256, 0, stream>>>(Wv, Wvb);
  proj_v128_kernel<<<dim3(64, 4), 256, 0, stream>>>(vb, Wvb, vT);

  // mask_prep overwrites region0 (Xq/Xk/W*/vb/Wvb are dead by now)
  mask_prep_kernel<<<dim3(B_ * N_), 256, 0, stream>>>(masks, mbf, msumb);
  attn_kernel<<<dim3(N_ / 128, H_, B_), 512, 0, stream>>>(qf, kf, vT, mbf, msumb, out);
}

// Round 21
// 182.789 us; speedup vs baseline: 1.4478x; 1.0061x over previous
//
#include <hip/hip_runtime.h>
#include <hip/hip_bf16.h>

#define B_ 4
#define N_ 2048
#define H_ 8
#define C_ 768
#define CV_ 512
#define DH_ 96
#define DV_ 64
// SCALE = 32^-0.5 = 2^-2.5 ; K2E = SCALE * log2(e) = 0.25503486...
#define K2E_ 0.2550348620270320f
// P-range bias (exact: cancels in O/Z): P = 2^(S-5)
#define PBIAS_ -5.0f

using bf16x8 = __attribute__((ext_vector_type(8))) short;
using f16x8  = __attribute__((ext_vector_type(8))) _Float16;
using f16x4  = __attribute__((ext_vector_type(4))) _Float16;
using h16x2  = __attribute__((ext_vector_type(2))) __fp16;
using f32x4  = __attribute__((ext_vector_type(4))) float;
using u16x4  = __attribute__((ext_vector_type(4))) unsigned short;

__device__ __forceinline__ unsigned short f2bf(float f) {
  union { float f; unsigned u; } x; x.f = f;
  unsigned r = x.u + 0x7fffu + ((x.u >> 16) & 1u);
  return (unsigned short)(r >> 16);
}
__device__ __forceinline__ void gload16(const void* g, void* l) {
  __builtin_amdgcn_global_load_lds(
      (const __attribute__((address_space(1))) void*)g,
      (__attribute__((address_space(3))) void*)l, 16, 0, 0);
}

#define MFMA_BF(a,b,c) __builtin_amdgcn_mfma_f32_16x16x32_bf16((a),(b),(c),0,0,0)
#define MFMA_F16(a,b,c) __builtin_amdgcn_mfma_f32_16x16x32_f16((a),(b),(c),0,0,0)

// ---------------------------------------------------------------------------
// f32 -> fp16 conversion, two tensors (blockIdx.y selects). 8 elems/thread.
// ---------------------------------------------------------------------------
__global__ __launch_bounds__(256) void convert2_f16_kernel(
    const float* __restrict__ in0, const float* __restrict__ in1,
    _Float16* __restrict__ o0, _Float16* __restrict__ o1)
{
  const float* in = blockIdx.y ? in1 : in0;
  _Float16* out = blockIdx.y ? o1 : o0;
  const size_t i8 = ((size_t)blockIdx.x * 256 + threadIdx.x) * 8;
  float4 v0 = *(const float4*)(in + i8);
  float4 v1 = *(const float4*)(in + i8 + 4);
  f16x8 o;
  o[0] = (_Float16)v0.x; o[1] = (_Float16)v0.y;
  o[2] = (_Float16)v0.z; o[3] = (_Float16)v0.w;
  o[4] = (_Float16)v1.x; o[5] = (_Float16)v1.y;
  o[6] = (_Float16)v1.z; o[7] = (_Float16)v1.w;
  *(f16x8*)(out + i8) = o;
}

// ---------------------------------------------------------------------------
// f32 -> bf16 conversion. 8 elems/thread.  (V-projection inputs stay bf16.)
// ---------------------------------------------------------------------------
__global__ __launch_bounds__(256) void convert_bf16_kernel(
    const float* __restrict__ in, unsigned short* __restrict__ out)
{
  const size_t i8 = ((size_t)blockIdx.x * 256 + threadIdx.x) * 8;
  float4 v0 = *(const float4*)(in + i8);
  float4 v1 = *(const float4*)(in + i8 + 4);
  u16x4 a, b;
  a[0] = f2bf(v0.x); a[1] = f2bf(v0.y); a[2] = f2bf(v0.z); a[3] = f2bf(v0.w);
  b[0] = f2bf(v1.x); b[1] = f2bf(v1.y); b[2] = f2bf(v1.z); b[3] = f2bf(v1.w);
  *(u16x4*)(out + i8) = a;
  *(u16x4*)(out + i8 + 4) = b;
}

// ---------------------------------------------------------------------------
// fp16 GEMM for Q and K projections in one dispatch (blockIdx.z selects).
// O = scale * (X @ W^T). 128x128 tile, BK=64, global_load_lds, linear LDS.
// Output fp16 at [(b*8+h)*2048+n]*96+d.  Q gets scale=K2E.
// ---------------------------------------------------------------------------
__global__ __launch_bounds__(256) void proj_qk2_kernel(
    const _Float16* __restrict__ Xq, const _Float16* __restrict__ Xk,
    const _Float16* __restrict__ Wqf, const _Float16* __restrict__ Wkf,
    _Float16* __restrict__ Oq, _Float16* __restrict__ Ok)
{
  __shared__ __align__(16) _Float16 Ah[128 * 64];
  __shared__ __align__(16) _Float16 Bh[128 * 64];

  const int zq = blockIdx.z;
  const _Float16* X = zq ? Xk : Xq;
  const _Float16* W = zq ? Wkf : Wqf;
  _Float16* O = zq ? Ok : Oq;
  const float scale = zq ? 1.0f : K2E_;

  const int mb = blockIdx.x * 128, nb = blockIdx.y * 128;
  const int t = threadIdx.x, w = t >> 6, lane = t & 63;
  const int fr = lane & 15, g = lane >> 4;
  const int wr = w >> 1, wc = w & 1;

  int offA[4], offB[4];
  unsigned ldsB[4];
#pragma unroll
  for (int j = 0; j < 4; ++j) {
    int lin = ((w * 4 + j) << 10) + (lane << 4);
    int r = lin >> 7, ce = (lin & 127) >> 1;
    offA[j] = (mb + r) * C_ + ce;
    offB[j] = (nb + r) * C_ + ce;
    ldsB[j] = (unsigned)((w * 4 + j) << 10);
  }

  f32x4 acc[4][4];
#pragma unroll
  for (int m = 0; m < 4; ++m)
#pragma unroll
    for (int n = 0; n < 4; ++n) acc[m][n] = (f32x4){0.f, 0.f, 0.f, 0.f};

  for (int kt = 0; kt < C_ / 64; ++kt) {
    const int kb = kt * 64;
    __syncthreads();
#pragma unroll
    for (int j = 0; j < 4; ++j) {
      gload16(X + offA[j] + kb, (char*)Ah + ldsB[j]);
      gload16(W + offB[j] + kb, (char*)Bh + ldsB[j]);
    }
    __syncthreads();
#pragma unroll
    for (int s = 0; s < 2; ++s) {
      const int cbyte = s * 64 + g * 16;
      f16x8 ah[4], bh2[4];
#pragma unroll
      for (int m = 0; m < 4; ++m)
        ah[m] = *(const f16x8*)((const char*)Ah + (wr * 64 + m * 16 + fr) * 128 + cbyte);
#pragma unroll
      for (int n = 0; n < 4; ++n)
        bh2[n] = *(const f16x8*)((const char*)Bh + (wc * 64 + n * 16 + fr) * 128 + cbyte);
#pragma unroll
      for (int m = 0; m < 4; ++m)
#pragma unroll
        for (int n = 0; n < 4; ++n)
          acc[m][n] = MFMA_F16(ah[m], bh2[n], acc[m][n]);
    }
  }

#pragma unroll
  for (int m = 0; m < 4; ++m) {
    const int Mrow = mb + wr * 64 + m * 16 + g * 4;
#pragma unroll
    for (int n = 0; n < 4; ++n) {
      const int co = nb + wc * 64 + n * 16 + fr;
      const int h = co / DH_, d = co - h * DH_;
#pragma unroll
      for (int r = 0; r < 4; ++r) {
        const int M = Mrow + r;
        const int b = M >> 11, nn = M & (N_ - 1);
        O[((size_t)((b * H_ + h) * N_ + nn)) * DH_ + d] = (_Float16)(acc[m][n][r] * scale);
      }
    }
  }
}

// ---------------------------------------------------------------------------
// V projection, 128x128 tile bf16 (m97 structure), storing V^T as f16:
// OvT[(b*8+h)*64 + d][n].  X:(8192,512) bf16, W:(512,512) bf16.
// ---------------------------------------------------------------------------
__global__ __launch_bounds__(256) void proj_v128_kernel(
    const unsigned short* __restrict__ X, const unsigned short* __restrict__ W,
    _Float16* __restrict__ OvT)
{
  __shared__ __align__(16) unsigned short Ah[128 * 64];
  __shared__ __align__(16) unsigned short Bh[128 * 64];

  const int mb = blockIdx.x * 128, nb = blockIdx.y * 128;
  const int t = threadIdx.x, w = t >> 6, lane = t & 63;
  const int fr = lane & 15, g = lane >> 4;
  const int wr = w >> 1, wc = w & 1;

  int offA[4], offB[4];
  unsigned ldsB[4];
#pragma unroll
  for (int j = 0; j < 4; ++j) {
    int lin = ((w * 4 + j) << 10) + (lane << 4);
    int r = lin >> 7, ce = (lin & 127) >> 1;
    offA[j] = (mb + r) * CV_ + ce;
    offB[j] = (nb + r) * CV_ + ce;
    ldsB[j] = (unsigned)((w * 4 + j) << 10);
  }

  f32x4 acc[4][4];
#pragma unroll
  for (int m = 0; m < 4; ++m)
#pragma unroll
    for (int n = 0; n < 4; ++n) acc[m][n] = (f32x4){0.f, 0.f, 0.f, 0.f};

  for (int kt = 0; kt < CV_ / 64; ++kt) {
    const int kb = kt * 64;
    __syncthreads();
#pragma unroll
    for (int j = 0; j < 4; ++j) {
      gload16(X + offA[j] + kb, (char*)Ah + ldsB[j]);
      gload16(W + offB[j] + kb, (char*)Bh + ldsB[j]);
    }
    __syncthreads();
#pragma unroll
    for (int s = 0; s < 2; ++s) {
      const int cbyte = s * 64 + g * 16;
      bf16x8 ah[4], bh2[4];
#pragma unroll
      for (int m = 0; m < 4; ++m)
        ah[m] = *(const bf16x8*)((const char*)Ah + (wr * 64 + m * 16 + fr) * 128 + cbyte);
#pragma unroll
      for (int n = 0; n < 4; ++n)
        bh2[n] = *(const bf16x8*)((const char*)Bh + (wc * 64 + n * 16 + fr) * 128 + cbyte);
#pragma unroll
      for (int m = 0; m < 4; ++m)
#pragma unroll
        for (int n = 0; n < 4; ++n)
          acc[m][n] = MFMA_BF(ah[m], bh2[n], acc[m][n]);
    }
  }

  // V^T store: 4 consecutive n per lane -> one b64 store (f16)
#pragma unroll
  for (int m = 0; m < 4; ++m) {
    const int M0 = mb + wr * 64 + m * 16 + g * 4;
    const int b = M0 >> 11, nn = M0 & (N_ - 1);
#pragma unroll
    for (int n = 0; n < 4; ++n) {
      const int co = nb + wc * 64 + n * 16 + fr;
      const int h = co >> 6, d = co & 63;
      f16x4 pk;
#pragma unroll
      for (int r = 0; r < 4; ++r) pk[r] = (_Float16)acc[m][n][r];
      *(f16x4*)(OvT + ((size_t)((b * H_ + h) * DV_ + d)) * N_ + nn) = pk;
    }
  }
}

// ---------------------------------------------------------------------------
// Mask pre-pass: f16 copy + per-row f32 sum. One block per (b,n) row.
// ---------------------------------------------------------------------------
__global__ __launch_bounds__(256) void mask_prep_kernel(
    const float* __restrict__ masks, _Float16* __restrict__ mask_f,
    float* __restrict__ msum)
{
  const int row = blockIdx.x;
  const int t = threadIdx.x;
  const float* p = masks + (size_t)row * N_;
  _Float16* o = mask_f + (size_t)row * N_;
  float4 v0 = *(const float4*)(p + t * 8);
  float4 v1 = *(const float4*)(p + t * 8 + 4);
  float s = v0.x + v0.y + v0.z + v0.w + v1.x + v1.y + v1.z + v1.w;
  f16x4 a, b;
  a[0] = (_Float16)v0.x; a[1] = (_Float16)v0.y;
  a[2] = (_Float16)v0.z; a[3] = (_Float16)v0.w;
  b[0] = (_Float16)v1.x; b[1] = (_Float16)v1.y;
  b[2] = (_Float16)v1.z; b[3] = (_Float16)v1.w;
  *(f16x4*)(o + t * 8) = a;
  *(f16x4*)(o + t * 8 + 4) = b;
#pragma unroll
  for (int ofs = 32; ofs > 0; ofs >>= 1) s += __shfl_down(s, ofs, 64);
  __shared__ float ws4[4];
  if ((t & 63) == 0) ws4[t >> 6] = s;
  __syncthreads();
  if (t == 0) msum[row] = ws4[0] + ws4[1] + ws4[2] + ws4[3];
}

// ---------------------------------------------------------------------------
// Attention: block = (qtile, h, b), 512 threads = 8 waves x 16 q-rows.
// Q/K fp16 (QK f16 MFMA); P/mask/V fp16 (PV f16 MFMA). sacc init = -5
// (exact bias, cancels in O/Z) keeps P in f16 range. Softmax epilogue:
// exp2 + cvt_pkrtz + v_pk_mul_f16 (no bf2f shifts / f32 muls).
// ---------------------------------------------------------------------------
__global__ __launch_bounds__(512, 4) void attn_kernel(
    const _Float16* __restrict__ Qf, const _Float16* __restrict__ Kf,
    const _Float16* __restrict__ VT,  const _Float16* __restrict__ mask_f,
    const float* __restrict__ msum, float* __restrict__ out)
{
  __shared__ __align__(16) _Float16 Ks[64][100];
  __shared__ __align__(16) _Float16 Vs[64][68];    // V^T tile: [d][k]
  __shared__ __align__(16) _Float16 Ps[128][68];   // P: [q][k_local]

  const int qbase = blockIdx.x * 128;
  const int h = blockIdx.y, b = blockIdx.z;
  const int t = threadIdx.x;
  const int w = t >> 6, lane = t & 63;
  const int fr = lane & 15, g = lane >> 4;
  const int kof = g * 8;

  const size_t bh = (size_t)(b * H_ + h);
  const _Float16* Kf_p = Kf + bh * N_ * DH_;
  const _Float16* VT_p = VT + bh * DV_ * N_;

  const int qrow = qbase + w * 16 + fr;
  const size_t mrow_base = ((size_t)b * N_ + qrow) * N_;

  f16x8 qh[3];
#pragma unroll
  for (int s = 0; s < 3; ++s)
    qh[s] = *(const f16x8*)(Qf + (bh * N_ + qrow) * DH_ + s * 32 + kof);

  // K tile: 64x96 f16 = 768 b128 chunks over 512 threads (t, and 512+t for t<256)
  // V tile: 64x64 f16 = 512 chunks, one per thread.
  const int kr0 = t / 12,         kc0 = (t % 12) * 8;
  const int kr1 = (512 + t) / 12, kc1 = ((512 + t) % 12) * 8;
  const int vr = t >> 3, vc = (t & 7) * 8;
  const bool has2 = (t < 256);

  f16x8 pk0, pk1, pv;
  auto load_regs = [&](int kb) {
    pk0 = *(const f16x8*)(Kf_p + (size_t)(kb + kr0) * DH_ + kc0);
    if (has2) pk1 = *(const f16x8*)(Kf_p + (size_t)(kb + kr1) * DH_ + kc1);
    pv = *(const f16x8*)(VT_p + (size_t)vr * N_ + kb + vc);
  };

  f32x4 oacc[4];
#pragma unroll
  for (int i = 0; i < 4; ++i) oacc[i] = (f32x4){0.f, 0.f, 0.f, 0.f};
  float z = 0.f;

  load_regs(0);

  for (int kt = 0; kt < N_ / 64; ++kt) {
    const int kb = kt * 64;
    __syncthreads();
    *(f16x8*)&Ks[kr0][kc0] = pk0;
    if (has2) *(f16x8*)&Ks[kr1][kc1] = pk1;
    *(f16x8*)&Vs[vr][vc] = pv;
    __syncthreads();

    if (kt + 1 < N_ / 64) load_regs(kb + 64);

    // mask loads early (b64 = 4 f16), consumed after QK
    uint2 mku[4];
#pragma unroll
    for (int a = 0; a < 4; ++a)
      mku[a] = *(const uint2*)(mask_f + mrow_base + kb + a * 16 + g * 4);

    // S^T = K * Q^T (f16): lane holds q=fr, k rows a*16+g*4+r.
    // Accumulator pre-biased to -5: P = 2^(S-5) (cancels in O/Z).
    f32x4 sacc[4];
#pragma unroll
    for (int a = 0; a < 4; ++a)
      sacc[a] = (f32x4){PBIAS_, PBIAS_, PBIAS_, PBIAS_};
#pragma unroll
    for (int s = 0; s < 3; ++s) {
#pragma unroll
      for (int a = 0; a < 4; ++a) {
        f16x8 kh = *(const f16x8*)&Ks[a * 16 + fr][s * 32 + kof];
        sacc[a] = MFMA_F16(kh, qh[s], sacc[a]);
      }
    }

    // P = exp2(S-5); Z += P (tree); Ps = f16(P) * f16(mask) via pk_mul
#pragma unroll
    for (int a = 0; a < 4; ++a) {
      float e0 = exp2f(sacc[a][0]);
      float e1 = exp2f(sacc[a][1]);
      float e2 = exp2f(sacc[a][2]);
      float e3 = exp2f(sacc[a][3]);
      z += (e0 + e1) + (e2 + e3);
      h16x2 pe01 = __builtin_amdgcn_cvt_pkrtz(e0, e1);
      h16x2 pe23 = __builtin_amdgcn_cvt_pkrtz(e2, e3);
      union { unsigned u; h16x2 h; } m01, m23, r01, r23;
      m01.u = mku[a].x; m23.u = mku[a].y;
      r01.h = pe01 * m01.h;
      r23.h = pe23 * m23.h;
      *(uint2*)&Ps[w * 16 + fr][a * 16 + g * 4] = make_uint2(r01.u, r23.u);
    }

    // O += P V  (Ps rows are wave-private: no barrier needed)
#pragma unroll
    for (int s2 = 0; s2 < 2; ++s2) {
      f16x8 pa = *(const f16x8*)&Ps[w * 16 + fr][s2 * 32 + kof];
#pragma unroll
      for (int dt = 0; dt < 4; ++dt) {
        f16x8 vb = *(const f16x8*)&Vs[dt * 16 + fr][s2 * 32 + kof];
        oacc[dt] = MFMA_F16(pa, vb, oacc[dt]);
      }
    }
  }

  // Z: reduce across the 4 k-row groups (lanes fr, fr+16, fr+32, fr+48)
  z += __shfl_xor(z, 16, 64);
  z += __shfl_xor(z, 32, 64);

  // epilogue: output rows are q16 = g*4+r; Z lives at lane fr=q16
#pragma unroll
  for (int r = 0; r < 4; ++r) {
    int q = qbase + w * 16 + g * 4 + r;
    float Z = __shfl(z, g * 4 + r, 64);
    float inv = 1.0f / (Z * 8.0f * msum[b * N_ + q]);
#pragma unroll
    for (int dt = 0; dt < 4; ++dt)
      out[((size_t)b * N_ + q) * CV_ + h * DV_ + dt * 16 + fr] = oacc[dt][r] * inv;
  }
}

// ---------------------------------------------------------------------------
extern "C" void kernel_launch(void* const* d_in, const int* in_sizes, int n_in,
                              void* d_out, int out_size, void* d_ws, size_t ws_size,
                              hipStream_t stream)
{
  (void)in_sizes; (void)n_in; (void)out_size; (void)ws_size;
  const float* q     = (const float*)d_in[0];
  const float* k     = (const float*)d_in[1];
  const float* v     = (const float*)d_in[2];
  const float* masks = (const float*)d_in[3];
  const float* Wq    = (const float*)d_in[4];
  const float* Wk    = (const float*)d_in[5];
  const float* Wv    = (const float*)d_in[6];
  float* out = (float*)d_out;

  char* ws = (char*)d_ws;
  const size_t qk_elems = (size_t)B_ * N_ * C_;        // 6,291,456
  const size_t w_elems  = (size_t)C_ * C_;             // 589,824
  const size_t v_elems  = (size_t)B_ * N_ * CV_;       // 4,194,304
  const size_t wv_elems = (size_t)CV_ * CV_;           // 262,144
  const size_t qk_bytes = qk_elems * 2;                // 12,582,912
  const size_t w_bytes  = w_elems * 2;                 // 1,179,648
  const size_t vb_bytes = v_elems * 2;                 // 8,388,608
  const size_t wv_bytes = wv_elems * 2;                // 524,288
  const size_t m_bytes  = (size_t)B_ * N_ * N_ * 2;    // 33,554,432

  // region0: proj-phase temporaries, later overwritten by mbf (mask_prep).
  _Float16* mbf = (_Float16*)ws;
  _Float16* Xq  = (_Float16*)ws;
  _Float16* Xk  = (_Float16*)(ws + qk_bytes);
  _Float16* Wqf = (_Float16*)(ws + 2 * qk_bytes);
  _Float16* Wkf = (_Float16*)(ws + 2 * qk_bytes + w_bytes);
  unsigned short* vb  = (unsigned short*)(ws + 2 * qk_bytes + 2 * w_bytes);
  unsigned short* Wvb = (unsigned short*)(ws + 2 * qk_bytes + 2 * w_bytes + vb_bytes);
  size_t r0 = 2 * qk_bytes + 2 * w_bytes + vb_bytes + wv_bytes; // 36.4 MB
  if (r0 < m_bytes) r0 = m_bytes;
  char* p = ws + r0;
  _Float16* qf = (_Float16*)p; p += qk_bytes;
  _Float16* kf = (_Float16*)p; p += qk_bytes;
  _Float16* vT = (_Float16*)p; p += vb_bytes;
  float* msumb = (float*)p;

  convert2_f16_kernel<<<dim3((int)(w_elems / 2048), 2), 256, 0, stream>>>(Wq, Wk, Wqf, Wkf);
  convert2_f16_kernel<<<dim3((int)(qk_elems / 2048), 2), 256, 0, stream>>>(q, k, Xq, Xk);
  proj_qk2_kernel<<<dim3(64, 6, 2), 256, 0, stream>>>(Xq, Xk, Wqf, Wkf, qf, kf);

  convert_bf16_kernel<<<dim3((int)(v_elems / 2048)), 256, 0, stream>>>(v, vb);
  convert_bf16_kernel<<<dim3((int)(wv_elems / 2048)), 256, 0, stream>>>(Wv, Wvb);
  proj_v128_kernel<<<dim3(64, 4), 256, 0, stream>>>(vb, Wvb, vT);

  // mask_prep overwrites region0 (Xq/Xk/W*/vb/Wvb are dead by now)
  mask_prep_kernel<<<dim3(B_ * N_), 256, 0, stream>>>(masks, mbf, msumb);
  attn_kernel<<<dim3(N_ / 128, H_, B_), 512, 0, stream>>>(qf, kf, vT, mbf, msumb, out);
}